// Round 19
// baseline (206.359 us; speedup 1.0000x reference)
//
#include <hip/hip_runtime.h>
#include <hip/hip_bf16.h>

#define B_ 4
#define K_ 512
#define D_ 768
#define DK_ 96
#define DG_ 96
#define H_ 8

typedef __attribute__((ext_vector_type(8))) __bf16 bf16x8;
typedef __attribute__((ext_vector_type(4))) float f32x4;

static __device__ __forceinline__ unsigned short f2bf(float x) {
  union { float f; unsigned int u; } v; v.f = x;
  unsigned int u = v.u;
  return (unsigned short)((u + 0x7FFFu + ((u >> 16) & 1u)) >> 16);
}

// ---------------- K0a: cast f_a -> bf16 ----------------
__global__ __launch_bounds__(256) void cast_fa_kernel(const float* __restrict__ fa,
                                                      unsigned short* __restrict__ fa16) {
  int t = blockIdx.x * 256 + threadIdx.x;   // n4 = B*K*D/4 = 393216
  float4 v = ((const float4*)fa)[t];
  ushort4 o;
  o.x = f2bf(v.x); o.y = f2bf(v.y); o.z = f2bf(v.z); o.w = f2bf(v.w);
  ((ushort4*)fa16)[t] = o;
}

// ---------------- K0b: W[p][h][d][f] -> wt16[p][h][f][d] (coalesced LDS transpose) ----------------
// grid: p(3)*h(8)*dt(6) = 144 blocks; tile = 128 d x 96 f
__global__ __launch_bounds__(256) void prep_w_kernel(const float* __restrict__ wq,
                                                     const float* __restrict__ wk,
                                                     const float* __restrict__ wv,
                                                     unsigned short* __restrict__ wt16) {
  __shared__ unsigned short Ts[96][130];
  int bid = blockIdx.x;
  int dt = bid % 6; int rest = bid / 6;
  int h = rest % 8; int p = rest / 8;
  const float* w = (p == 0) ? wq : (p == 1) ? wk : wv;
  const float* src = w + ((size_t)h * D_ + dt * 128) * DK_;   // 128 rows(d) x 96(f), coalesced
  for (int c = threadIdx.x; c < 128 * 96; c += 256) {
    int dd = c / 96, f = c % 96;
    Ts[f][dd] = f2bf(src[c]);
  }
  __syncthreads();
  unsigned short* dst = wt16 + (size_t)(p * H_ + h) * DK_ * D_ + dt * 128;
  for (int c = threadIdx.x; c < 96 * 32; c += 256) {    // 32 ushort4 per f-row
    int f = c / 32, q = c % 32;
    ushort4 v;
    v.x = Ts[f][q * 4 + 0]; v.y = Ts[f][q * 4 + 1];
    v.z = Ts[f][q * 4 + 2]; v.w = Ts[f][q * 4 + 3];
    *(ushort4*)(dst + (size_t)f * D_ + q * 4) = v;
  }
}

// ---------------- K1 MEGA: gate (pe->G) CONCURRENT WITH proj ----------------
// 512 threads, grid 640. bid%5<2 -> gate block (256 total), else proj (384).
// Gate path = R7 structure: wave = one i-row, streams its 196KB pe row
// sequentially; butterfly reduce-scatter over heads; G[b][h][j][i] fp32 via
// 18KB LDS transpose tile. BW-bound.
// Proj path = 8-wave direct-load GEMM (16 rows/wave), p==2 transposes its
// output tile through LDS -> vt16. Latency-bound -> overlaps with gate.
__global__ __launch_bounds__(512) void mega_kernel(
    const float* __restrict__ pe, const float* __restrict__ wgw,
    const float* __restrict__ wgb, float* __restrict__ G,
    const unsigned short* __restrict__ fa16, const unsigned short* __restrict__ wt16,
    const float* __restrict__ bq, const float* __restrict__ bk, const float* __restrict__ bv,
    unsigned short* __restrict__ q16, unsigned short* __restrict__ k16,
    unsigned short* __restrict__ vt16) {
  __shared__ alignas(16) char SMEM[96 * 130 * 2];   // 25KB union: Gs (18KB) / Ts
  int bid = blockIdx.x;
  int t = threadIdx.x;
  int lane = t & 63;

  if (bid % 5 < 2) {
    // ---------------- gate path (R7 verbatim geometry) ----------------
    float* Gs = (float*)SMEM;                // [64][8][9]
    int gid = (bid / 5) * 2 + (bid % 5);     // 0..255
    int b = gid >> 6;
    int i0 = (gid & 63) * 8;
    int wv = t >> 6;
    int grp = lane >> 3, lg3 = lane & 7;
    int b0 = lg3 & 1, b1 = (lg3 >> 1) & 1, b2 = (lg3 >> 2) & 1;
    int i = i0 + wv;
    float wb = wgb[lg3];
    const float4* wg4 = (const float4*)wgw;
    const float4* per = (const float4*)(pe + (size_t)(b * K_ + i) * K_ * DG_);

    for (int jt = 0; jt < 32; jt++) {
      int jb16 = jt * 16;
      float4 pev[2][3];
#pragma unroll
      for (int w2 = 0; w2 < 2; w2++) {
        int j = jb16 + grp * 2 + w2;
#pragma unroll
        for (int c = 0; c < 3; c++) pev[w2][c] = per[j * 24 + lg3 + 8 * c];
      }
#pragma unroll
      for (int w2 = 0; w2 < 2; w2++) {
        float v[8];
#pragma unroll
        for (int h = 0; h < 8; h++) {
          float4 w0 = wg4[h * 24 + lg3];
          float4 w1 = wg4[h * 24 + lg3 + 8];
          float4 w2v = wg4[h * 24 + lg3 + 16];
          v[h] = pev[w2][0].x * w0.x + pev[w2][0].y * w0.y
               + pev[w2][0].z * w0.z + pev[w2][0].w * w0.w
               + pev[w2][1].x * w1.x + pev[w2][1].y * w1.y
               + pev[w2][1].z * w1.z + pev[w2][1].w * w1.w
               + pev[w2][2].x * w2v.x + pev[w2][2].y * w2v.y
               + pev[w2][2].z * w2v.z + pev[w2][2].w * w2v.w;
        }
        // butterfly reduce-scatter: lane lg3 ends with full sum for head h = lg3
        float r1[4], r2[2];
#pragma unroll
        for (int m = 0; m < 4; m++) {
          float keep = b0 ? v[2 * m + 1] : v[2 * m];
          float send = b0 ? v[2 * m]     : v[2 * m + 1];
          r1[m] = keep + __shfl_xor(send, 1);
        }
#pragma unroll
        for (int n = 0; n < 2; n++) {
          float keep = b1 ? r1[2 * n + 1] : r1[2 * n];
          float send = b1 ? r1[2 * n]     : r1[2 * n + 1];
          r2[n] = keep + __shfl_xor(send, 2);
        }
        float keep = b2 ? r2[1] : r2[0];
        float send = b2 ? r2[0] : r2[1];
        float g = keep + __shfl_xor(send, 4);
        float lgt = __logf(fmaxf(g + wb, 1e-6f));  // relu+clip == max(.,1e-6)
        int j64 = (jb16 & 63) + grp * 2 + w2;
        Gs[(j64 * 8 + lg3) * 9 + wv] = lgt;
      }
      if ((jt & 3) == 3) {
        __syncthreads();
        int jb = (jt - 3) * 16;
        int ii = t & 7, j64 = t >> 3;
#pragma unroll
        for (int h = 0; h < 8; h++)
          G[((size_t)(b * H_ + h) * K_ + jb + j64) * K_ + i0 + ii] =
              Gs[(j64 * 8 + h) * 9 + ii];
        __syncthreads();
      }
    }
  } else {
    // ---------------- proj path (8 waves x 16 rows, direct-load GEMM) ----------------
    int pid = (bid / 5) * 3 + (bid % 5 - 2);   // 0..383
    int ph = pid >> 4;                          // 0..23
    int mt16 = pid & 15;
    int b = mt16 >> 2, mt = mt16 & 3;
    int p = ph >> 3, h = ph & 7;
    int wid = t >> 6;
    int lr = lane & 15, lg = lane >> 4;
    int row0 = mt * 128 + wid * 16;             // wave owns 16 rows

    const unsigned short* A  = fa16 + ((size_t)(b * K_ + row0)) * D_;
    const unsigned short* Bt = wt16 + (size_t)ph * DK_ * D_;

    f32x4 acc[6];
#pragma unroll
    for (int c = 0; c < 6; c++) acc[c] = (f32x4){0.f, 0.f, 0.f, 0.f};

    for (int kk = 0; kk < 24; kk++) {
      bf16x8 a = *(const bf16x8*)(A + (size_t)lr * D_ + kk * 32 + lg * 8);
#pragma unroll
      for (int c = 0; c < 6; c++) {
        bf16x8 bb = *(const bf16x8*)(Bt + (size_t)(c * 16 + lr) * D_ + kk * 32 + lg * 8);
        acc[c] = __builtin_amdgcn_mfma_f32_16x16x32_bf16(a, bb, acc[c], 0, 0, 0);
      }
    }

    const float* bias = (p == 0) ? bq : (p == 1) ? bk : bv;
    if (p == 2) {
      unsigned short* Tp = (unsigned short*)SMEM;   // [96][130]
#pragma unroll
      for (int c = 0; c < 6; c++) {
        int col = c * 16 + lr;
        float bb = bias[h * DK_ + col];
#pragma unroll
        for (int r = 0; r < 4; r++) {
          int lrow = wid * 16 + lg * 4 + r;
          Tp[col * 130 + lrow] = f2bf(acc[c][r] + bb);
        }
      }
      __syncthreads();
      unsigned short* dst = vt16 + (size_t)(b * H_ + h) * DK_ * K_ + mt * 128;
      for (int c2 = t; c2 < 96 * 32; c2 += 512) {
        int f = c2 / 32, q = c2 % 32;
        ushort4 v;
        v.x = Tp[f * 130 + q * 4 + 0]; v.y = Tp[f * 130 + q * 4 + 1];
        v.z = Tp[f * 130 + q * 4 + 2]; v.w = Tp[f * 130 + q * 4 + 3];
        *(ushort4*)(dst + (size_t)f * K_ + q * 4) = v;
      }
    } else {
      unsigned short* dst = (p == 0) ? q16 : k16;
#pragma unroll
      for (int c = 0; c < 6; c++) {
        int col = c * 16 + lr;
        float bb = bias[h * DK_ + col];
#pragma unroll
        for (int r = 0; r < 4; r++) {
          int row = row0 + lg * 4 + r;
          dst[((size_t)(b * H_ + h) * K_ + row) * DK_ + col] = f2bf(acc[c][r] + bb);
        }
      }
    }
  }
}

// ---------------- K2: scores  L[b][h][j][i] = q[j]·k[i]/sqrt(96)  (XCD-swizzled) ----------------
// grid 512. xcd = bid&7; 4 (b,h) pairs per XCD, 16 tiles each.
__global__ __launch_bounds__(256) void scores_kernel(const unsigned short* __restrict__ q16,
                                                     const unsigned short* __restrict__ k16,
                                                     float* __restrict__ L) {
  int bid = blockIdx.x;
  int xcd = bid & 7, loc = bid >> 3;      // 64 per XCD
  int bh = ((loc >> 4) << 3) | xcd;       // 4 bh per XCD
  int jt = (loc >> 2) & 3, it = loc & 3;
  int b = bh >> 3, h = bh & 7;
  int lane = threadIdx.x & 63, wid = threadIdx.x >> 6;
  int lr = lane & 15, lg = lane >> 4;
  int j0 = jt * 128 + wid * 32;
  int i0 = it * 128;
  const unsigned short* Q  = q16 + ((size_t)(b * H_ + h) * K_ + j0) * DK_;
  const unsigned short* Kp = k16 + ((size_t)(b * H_ + h) * K_ + i0) * DK_;

  f32x4 acc[2][8];
#pragma unroll
  for (int x = 0; x < 2; x++)
#pragma unroll
    for (int c = 0; c < 8; c++) acc[x][c] = (f32x4){0.f, 0.f, 0.f, 0.f};

#pragma unroll
  for (int kk = 0; kk < 3; kk++) {
    bf16x8 a0 = *(const bf16x8*)(Q + (size_t)lr * DK_ + kk * 32 + lg * 8);
    bf16x8 a1 = *(const bf16x8*)(Q + (size_t)(16 + lr) * DK_ + kk * 32 + lg * 8);
#pragma unroll
    for (int c = 0; c < 8; c++) {
      bf16x8 bfr = *(const bf16x8*)(Kp + (size_t)(c * 16 + lr) * DK_ + kk * 32 + lg * 8);
      acc[0][c] = __builtin_amdgcn_mfma_f32_16x16x32_bf16(a0, bfr, acc[0][c], 0, 0, 0);
      acc[1][c] = __builtin_amdgcn_mfma_f32_16x16x32_bf16(a1, bfr, acc[1][c], 0, 0, 0);
    }
  }

  const float scale = 0.10206207261596577f;  // 1/sqrt(96)
  float* Lb = L + ((size_t)(b * H_ + h) * K_ + j0) * K_ + i0;
#pragma unroll
  for (int x = 0; x < 2; x++)
#pragma unroll
    for (int c = 0; c < 8; c++)
#pragma unroll
      for (int r = 0; r < 4; r++) {
        int jl = x * 16 + lg * 4 + r;
        int il = c * 16 + lr;
        Lb[(size_t)jl * K_ + il] = acc[x][c][r] * scale;
      }
}

// ---------------- K3: softmax over i: logits = G + L; write attn bf16 ----------------
__global__ __launch_bounds__(256) void softmax_kernel(const float* __restrict__ G,
                                                      const float* __restrict__ L,
                                                      unsigned short* __restrict__ p16) {
  int wid = threadIdx.x >> 6, lane = threadIdx.x & 63;
  int row = blockIdx.x * 4 + wid;  // B*H*K = 16384 rows of (b,h,j)
  const float4* g4 = (const float4*)(G + (size_t)row * K_);
  const float4* s4 = (const float4*)(L + (size_t)row * K_);
  float4 g0 = g4[lane], g1 = g4[lane + 64];
  float4 s0 = s4[lane], s1 = s4[lane + 64];
  float l0 = g0.x + s0.x, l1 = g0.y + s0.y, l2 = g0.z + s0.z, l3 = g0.w + s0.w;
  float l4 = g1.x + s1.x, l5 = g1.y + s1.y, l6 = g1.z + s1.z, l7 = g1.w + s1.w;
  float m = fmaxf(fmaxf(fmaxf(l0, l1), fmaxf(l2, l3)),
                  fmaxf(fmaxf(l4, l5), fmaxf(l6, l7)));
#pragma unroll
  for (int o = 32; o > 0; o >>= 1) m = fmaxf(m, __shfl_xor(m, o));
  float e0 = __expf(l0 - m), e1 = __expf(l1 - m), e2 = __expf(l2 - m), e3 = __expf(l3 - m);
  float e4 = __expf(l4 - m), e5 = __expf(l5 - m), e6 = __expf(l6 - m), e7 = __expf(l7 - m);
  float s = ((e0 + e1) + (e2 + e3)) + ((e4 + e5) + (e6 + e7));
#pragma unroll
  for (int o = 32; o > 0; o >>= 1) s += __shfl_xor(s, o);
  float inv = 1.0f / s;
  ushort4 o0, o1;
  o0.x = f2bf(e0 * inv); o0.y = f2bf(e1 * inv); o0.z = f2bf(e2 * inv); o0.w = f2bf(e3 * inv);
  o1.x = f2bf(e4 * inv); o1.y = f2bf(e5 * inv); o1.z = f2bf(e6 * inv); o1.w = f2bf(e7 * inv);
  ushort4* dst = (ushort4*)(p16 + (size_t)row * K_);
  dst[lane] = o0;
  dst[lane + 64] = o1;
}

// ---------------- K5: PV GEMM + epilogue (XCD-swizzled)  out = gamma*(attn·v)+f_a ----------------
// grid 256. xcd = bid&7; 4 (b,h) per XCD, 8 mt each.
__global__ __launch_bounds__(256) void pv_kernel(const unsigned short* __restrict__ p16,
                                                 const unsigned short* __restrict__ vt16,
                                                 const float* __restrict__ fa,
                                                 const float* __restrict__ gptr,
                                                 float* __restrict__ out) {
  int bid = blockIdx.x;
  int xcd = bid & 7, loc = bid >> 3;      // 32 per XCD
  int bh = ((loc >> 3) << 3) | xcd;       // 4 bh per XCD
  int mt = loc & 7;
  int b = bh >> 3, h = bh & 7;
  int lane = threadIdx.x & 63, wid = threadIdx.x >> 6;
  int lr = lane & 15, lg = lane >> 4;
  int row0 = mt * 64 + wid * 16;
  const unsigned short* A = p16 + ((size_t)bh * K_ + row0) * K_;
  const unsigned short* V = vt16 + (size_t)bh * DK_ * K_;

  f32x4 acc[6];
#pragma unroll
  for (int c = 0; c < 6; c++) acc[c] = (f32x4){0.f, 0.f, 0.f, 0.f};

  for (int kk = 0; kk < 16; kk++) {
    bf16x8 a = *(const bf16x8*)(A + (size_t)lr * K_ + kk * 32 + lg * 8);
#pragma unroll
    for (int c = 0; c < 6; c++) {
      bf16x8 bfr = *(const bf16x8*)(V + (size_t)(c * 16 + lr) * K_ + kk * 32 + lg * 8);
      acc[c] = __builtin_amdgcn_mfma_f32_16x16x32_bf16(a, bfr, acc[c], 0, 0, 0);
    }
  }

  float gamma = gptr[0];
#pragma unroll
  for (int c = 0; c < 6; c++) {
    int fcol = c * 16 + lr;
#pragma unroll
    for (int r = 0; r < 4; r++) {
      int j = row0 + lg * 4 + r;
      size_t oidx = ((size_t)(b * K_ + j)) * D_ + h * DK_ + fcol;
      out[oidx] = gamma * acc[c][r] + fa[oidx];
    }
  }
}

extern "C" void kernel_launch(void* const* d_in, const int* in_sizes, int n_in,
                              void* d_out, int out_size, void* d_ws, size_t ws_size,
                              hipStream_t stream) {
  (void)in_sizes; (void)n_in; (void)out_size; (void)ws_size;
  const float* fa   = (const float*)d_in[0];
  const float* pe   = (const float*)d_in[1];
  const float* wgw  = (const float*)d_in[2];
  const float* wgb  = (const float*)d_in[3];
  const float* wkw  = (const float*)d_in[4];
  const float* wkb  = (const float*)d_in[5];
  const float* wqw  = (const float*)d_in[6];
  const float* wqb  = (const float*)d_in[7];
  const float* wvw  = (const float*)d_in[8];
  const float* wvb  = (const float*)d_in[9];
  const float* gptr = (const float*)d_in[10];
  float* out = (float*)d_out;

  char* ws = (char*)d_ws;
  unsigned short* fa16 = (unsigned short*)ws; ws += (size_t)B_ * K_ * D_ * 2;
  unsigned short* wt16 = (unsigned short*)ws; ws += (size_t)3 * H_ * DK_ * D_ * 2;
  unsigned short* q16  = (unsigned short*)ws; ws += (size_t)B_ * H_ * K_ * DK_ * 2;
  unsigned short* k16  = (unsigned short*)ws; ws += (size_t)B_ * H_ * K_ * DK_ * 2;
  unsigned short* vt16 = (unsigned short*)ws; ws += (size_t)B_ * H_ * DK_ * K_ * 2;
  float* L             = (float*)ws;          ws += (size_t)B_ * H_ * K_ * K_ * 4;
  float* G             = (float*)ws;          ws += (size_t)B_ * H_ * K_ * K_ * 4;
  unsigned short* p16  = (unsigned short*)ws;

  cast_fa_kernel<<<(B_ * K_ * D_ / 4) / 256, 256, 0, stream>>>(fa, fa16);
  prep_w_kernel<<<144, 256, 0, stream>>>(wqw, wkw, wvw, wt16);
  mega_kernel<<<640, 512, 0, stream>>>(pe, wgw, wgb, G, fa16, wt16,
                                       wqb, wkb, wvb, q16, k16, vt16);
  scores_kernel<<<512, 256, 0, stream>>>(q16, k16, L);
  softmax_kernel<<<(B_ * H_ * K_) / 4, 256, 0, stream>>>(G, L, p16);
  pv_kernel<<<256, 256, 0, stream>>>(p16, vt16, fa, gptr, out);
}

// Round 20
// 181.457 us; speedup vs baseline: 1.1372x; 1.1372x over previous
//
#include <hip/hip_runtime.h>
#include <hip/hip_bf16.h>

#define B_ 4
#define K_ 512
#define D_ 768
#define DK_ 96
#define DG_ 96
#define H_ 8

typedef __attribute__((ext_vector_type(8))) __bf16 bf16x8;
typedef __attribute__((ext_vector_type(4))) float f32x4;

static __device__ __forceinline__ unsigned short f2bf(float x) {
  union { float f; unsigned int u; } v; v.f = x;
  unsigned int u = v.u;
  return (unsigned short)((u + 0x7FFFu + ((u >> 16) & 1u)) >> 16);
}
static __device__ __forceinline__ float bf2f(unsigned short u) {
  union { unsigned int u; float f; } v; v.u = ((unsigned int)u) << 16;
  return v.f;
}

// ---------------- K0: fused cast f_a -> bf16  +  W transpose -> bf16 ----------------
// blocks [0,1536): cast fa (float4 -> ushort4). blocks [1536,1680): W transpose.
__global__ __launch_bounds__(256) void prep_kernel(const float* __restrict__ fa,
                                                   unsigned short* __restrict__ fa16,
                                                   const float* __restrict__ wq,
                                                   const float* __restrict__ wk,
                                                   const float* __restrict__ wv,
                                                   unsigned short* __restrict__ wt16) {
  __shared__ unsigned short Ts[96][130];
  if (blockIdx.x < 1536) {
    int t = blockIdx.x * 256 + threadIdx.x;   // n4 = B*K*D/4 = 393216
    float4 v = ((const float4*)fa)[t];
    ushort4 o;
    o.x = f2bf(v.x); o.y = f2bf(v.y); o.z = f2bf(v.z); o.w = f2bf(v.w);
    ((ushort4*)fa16)[t] = o;
  } else {
    int bid = blockIdx.x - 1536;              // 144 blocks: p(3)*h(8)*dt(6)
    int dt = bid % 6; int rest = bid / 6;
    int h = rest % 8; int p = rest / 8;
    const float* w = (p == 0) ? wq : (p == 1) ? wk : wv;
    const float* src = w + ((size_t)h * D_ + dt * 128) * DK_;  // 128 d x 96 f, coalesced
    for (int c = threadIdx.x; c < 128 * 96; c += 256) {
      int dd = c / 96, f = c % 96;
      Ts[f][dd] = f2bf(src[c]);
    }
    __syncthreads();
    unsigned short* dst = wt16 + (size_t)(p * H_ + h) * DK_ * D_ + dt * 128;
    for (int c = threadIdx.x; c < 96 * 32; c += 256) {
      int f = c / 32, q = c % 32;
      ushort4 v;
      v.x = Ts[f][q * 4 + 0]; v.y = Ts[f][q * 4 + 1];
      v.z = Ts[f][q * 4 + 2]; v.w = Ts[f][q * 4 + 3];
      *(ushort4*)(dst + (size_t)f * D_ + q * 4) = v;
    }
  }
}

// ---------------- K1: projections (bf16 MFMA, 1-ahead prefetch, XCD-swizzled) ----------------
// grid 384. xcd = bid&7 owns (b = xcd>>1, half of the 24 ph panels).
// p==2 (V) transposes its own 128x96 output tile through LDS -> vt16 directly.
__global__ __launch_bounds__(256) void proj_kernel(
    const unsigned short* __restrict__ fa16, const unsigned short* __restrict__ wt16,
    const float* __restrict__ bq, const float* __restrict__ bk, const float* __restrict__ bv,
    unsigned short* __restrict__ q16, unsigned short* __restrict__ k16,
    unsigned short* __restrict__ vt16) {
  __shared__ unsigned short Ts[96][130];   // used only by p==2 epilogue
  int bid = blockIdx.x;
  int xcd = bid & 7, loc = bid >> 3;  // XCD-aware mapping (bijective over 384)
  int b = xcd >> 1, half = xcd & 1;
  int ph = half * 12 + (loc >> 2);    // 12 panels per XCD
  int mt = loc & 3;
  int p = ph >> 3, h = ph & 7;
  int lane = threadIdx.x & 63, wid = threadIdx.x >> 6;
  int lr = lane & 15, lg = lane >> 4;
  int row0 = mt * 128 + wid * 32;     // wave owns 32 rows (2 m-frags)

  const unsigned short* A  = fa16 + ((size_t)(b * K_ + row0)) * D_;
  const unsigned short* Bt = wt16 + (size_t)ph * DK_ * D_;

  f32x4 acc[2][6];
#pragma unroll
  for (int i = 0; i < 2; i++)
#pragma unroll
    for (int c = 0; c < 6; c++) acc[i][c] = (f32x4){0.f, 0.f, 0.f, 0.f};

  auto LOADF = [&](bf16x8& a0, bf16x8& a1, bf16x8 (&bb)[6], int kk) {
    a0 = *(const bf16x8*)(A + (size_t)lr * D_ + kk * 32 + lg * 8);
    a1 = *(const bf16x8*)(A + (size_t)(16 + lr) * D_ + kk * 32 + lg * 8);
#pragma unroll
    for (int c = 0; c < 6; c++)
      bb[c] = *(const bf16x8*)(Bt + (size_t)(c * 16 + lr) * D_ + kk * 32 + lg * 8);
  };
  auto MF = [&](bf16x8& a0, bf16x8& a1, bf16x8 (&bb)[6]) {
#pragma unroll
    for (int c = 0; c < 6; c++) {
      acc[0][c] = __builtin_amdgcn_mfma_f32_16x16x32_bf16(a0, bb[c], acc[0][c], 0, 0, 0);
      acc[1][c] = __builtin_amdgcn_mfma_f32_16x16x32_bf16(a1, bb[c], acc[1][c], 0, 0, 0);
    }
  };

  bf16x8 a0X, a1X, bX[6], a0Y, a1Y, bY[6];
  LOADF(a0X, a1X, bX, 0);
  for (int kk = 0; kk < 24; kk += 2) {          // D/32 = 24 K-steps, ping-pong
    LOADF(a0Y, a1Y, bY, kk + 1);
    MF(a0X, a1X, bX);
    if (kk + 2 < 24) LOADF(a0X, a1X, bX, kk + 2);
    MF(a0Y, a1Y, bY);
  }

  const float* bias = (p == 0) ? bq : (p == 1) ? bk : bv;
  if (p == 2) {
    // V: transpose 128x96 tile through LDS, write vt16 [bh][f][i] coalesced
#pragma unroll
    for (int i = 0; i < 2; i++)
#pragma unroll
      for (int c = 0; c < 6; c++) {
        int col = c * 16 + lr;
        float bb = bias[h * DK_ + col];
#pragma unroll
        for (int r = 0; r < 4; r++) {
          int lrow = wid * 32 + i * 16 + lg * 4 + r;
          Ts[col][lrow] = f2bf(acc[i][c][r] + bb);
        }
      }
    __syncthreads();
    unsigned short* dst = vt16 + (size_t)(b * H_ + h) * DK_ * K_ + mt * 128;
    for (int c2 = threadIdx.x; c2 < 96 * 32; c2 += 256) {
      int f = c2 / 32, q = c2 % 32;
      ushort4 v;
      v.x = Ts[f][q * 4 + 0]; v.y = Ts[f][q * 4 + 1];
      v.z = Ts[f][q * 4 + 2]; v.w = Ts[f][q * 4 + 3];
      *(ushort4*)(dst + (size_t)f * K_ + q * 4) = v;
    }
  } else {
    unsigned short* dst = (p == 0) ? q16 : k16;
#pragma unroll
    for (int i = 0; i < 2; i++)
#pragma unroll
      for (int c = 0; c < 6; c++) {
        int col = c * 16 + lr;
        float bb = bias[h * DK_ + col];
#pragma unroll
        for (int r = 0; r < 4; r++) {
          int row = row0 + i * 16 + lg * 4 + r;
          dst[((size_t)(b * H_ + h) * K_ + row) * DK_ + col] = f2bf(acc[i][c][r] + bb);
        }
      }
  }
}

// ---------------- K2: scores L16[b][h][j][i] = bf16(q[j]·k[i]/sqrt(96))  (XCD-swizzled) ----------------
// grid 512. xcd = bid&7; 4 (b,h) pairs per XCD, 16 tiles each. bf16 store halves L traffic.
__global__ __launch_bounds__(256) void scores_kernel(const unsigned short* __restrict__ q16,
                                                     const unsigned short* __restrict__ k16,
                                                     unsigned short* __restrict__ L16) {
  int bid = blockIdx.x;
  int xcd = bid & 7, loc = bid >> 3;      // 64 per XCD
  int bh = ((loc >> 4) << 3) | xcd;       // 4 bh per XCD
  int jt = (loc >> 2) & 3, it = loc & 3;
  int b = bh >> 3, h = bh & 7;
  int lane = threadIdx.x & 63, wid = threadIdx.x >> 6;
  int lr = lane & 15, lg = lane >> 4;
  int j0 = jt * 128 + wid * 32;
  int i0 = it * 128;
  const unsigned short* Q  = q16 + ((size_t)(b * H_ + h) * K_ + j0) * DK_;
  const unsigned short* Kp = k16 + ((size_t)(b * H_ + h) * K_ + i0) * DK_;

  f32x4 acc[2][8];
#pragma unroll
  for (int x = 0; x < 2; x++)
#pragma unroll
    for (int c = 0; c < 8; c++) acc[x][c] = (f32x4){0.f, 0.f, 0.f, 0.f};

#pragma unroll
  for (int kk = 0; kk < 3; kk++) {
    bf16x8 a0 = *(const bf16x8*)(Q + (size_t)lr * DK_ + kk * 32 + lg * 8);
    bf16x8 a1 = *(const bf16x8*)(Q + (size_t)(16 + lr) * DK_ + kk * 32 + lg * 8);
#pragma unroll
    for (int c = 0; c < 8; c++) {
      bf16x8 bfr = *(const bf16x8*)(Kp + (size_t)(c * 16 + lr) * DK_ + kk * 32 + lg * 8);
      acc[0][c] = __builtin_amdgcn_mfma_f32_16x16x32_bf16(a0, bfr, acc[0][c], 0, 0, 0);
      acc[1][c] = __builtin_amdgcn_mfma_f32_16x16x32_bf16(a1, bfr, acc[1][c], 0, 0, 0);
    }
  }

  const float scale = 0.10206207261596577f;  // 1/sqrt(96)
  unsigned short* Lb = L16 + ((size_t)(b * H_ + h) * K_ + j0) * K_ + i0;
#pragma unroll
  for (int x = 0; x < 2; x++)
#pragma unroll
    for (int c = 0; c < 8; c++)
#pragma unroll
      for (int r = 0; r < 4; r++) {
        int jl = x * 16 + lg * 4 + r;
        int il = c * 16 + lr;
        Lb[(size_t)jl * K_ + il] = f2bf(acc[x][c][r] * scale);
      }
}

// ---------------- K3: fused gate + softmax (R4 structure; L read as bf16) ----------------
// grid: b(4) * jslab(128), jslab = 4 j-columns; 512 threads.
// Phase A: 8 lanes cooperate per pe row (lane&7 = g-chunk) -> 16 lines/instr.
// LDS: gate-logits [32 rows][516 pad] fp32 = 66 KB -> 2 blocks/CU.
#define GS_PAD 516
__global__ __launch_bounds__(512) void gatesm_kernel(
    const float* __restrict__ pe, const float* __restrict__ wgw,
    const float* __restrict__ wgb, const unsigned short* __restrict__ L16,
    unsigned short* __restrict__ p16) {
  extern __shared__ float Ls[];
  int b = blockIdx.x >> 7;
  int j0 = (blockIdx.x & 127) * 4;
  int t = threadIdx.x;
  int wv = t >> 6, lane = t & 63;
  int lr3 = (lane >> 3) & 7;   // row-in-pass
  int lg3 = lane & 7;          // g-chunk (of 24 float4 chunks, this lane does lg3, lg3+8, lg3+16)
  const float4* pe4 = (const float4*)pe;
  const float4* wg4 = (const float4*)wgw;

  // --- Phase A: gate logits -> LDS ---
  for (int p = 0; p < 8; p++) {
    int i = wv * 64 + p * 8 + lr3;
    float4 pev[4][3];
#pragma unroll
    for (int j = 0; j < 4; j++) {
      size_t base = ((size_t)(b * K_ + i) * K_ + (j0 + j)) * (DG_ / 4);
#pragma unroll
      for (int c = 0; c < 3; c++) pev[j][c] = pe4[base + lg3 + 8 * c];
    }
#pragma unroll
    for (int h = 0; h < H_; h++) {
      float4 w0 = wg4[h * 24 + lg3];
      float4 w1 = wg4[h * 24 + lg3 + 8];
      float4 w2 = wg4[h * 24 + lg3 + 16];
      float bias = wgb[h];
      float acc[4];
#pragma unroll
      for (int j = 0; j < 4; j++) {
        acc[j] = pev[j][0].x * w0.x + pev[j][0].y * w0.y + pev[j][0].z * w0.z + pev[j][0].w * w0.w
               + pev[j][1].x * w1.x + pev[j][1].y * w1.y + pev[j][1].z * w1.z + pev[j][1].w * w1.w
               + pev[j][2].x * w2.x + pev[j][2].y * w2.y + pev[j][2].z * w2.z + pev[j][2].w * w2.w;
      }
#pragma unroll
      for (int j = 0; j < 4; j++) {
        acc[j] += __shfl_xor(acc[j], 1);
        acc[j] += __shfl_xor(acc[j], 2);
        acc[j] += __shfl_xor(acc[j], 4);
      }
      if (lg3 == h) {   // h is a literal per unrolled iteration -> static predication
#pragma unroll
        for (int j = 0; j < 4; j++) {
          float lgt = __logf(fmaxf(acc[j] + bias, 1e-6f));  // relu+clip == max(.,1e-6)
          Ls[(h * 4 + j) * GS_PAD + i] = lgt;
        }
      }
    }
  }
  __syncthreads();

  // --- Phase B: logits = LDS gate + bf16 global scores; softmax over i; write p16 ---
#pragma unroll
  for (int rr = 0; rr < 4; rr++) {
    int row = wv * 4 + rr;          // 32 rows = (h, j)
    int h = row >> 2, j = row & 3;
    const float* Lr = &Ls[row * GS_PAD];
    const unsigned short* Lg = L16 + ((size_t)(b * H_ + h) * K_ + (j0 + j)) * K_;
    float4 g0 = *(const float4*)(Lr + lane * 4);
    float4 g1 = *(const float4*)(Lr + 256 + lane * 4);
    ushort4 s0 = *(const ushort4*)(Lg + lane * 4);
    ushort4 s1 = *(const ushort4*)(Lg + 256 + lane * 4);
    float l0 = g0.x + bf2f(s0.x), l1 = g0.y + bf2f(s0.y);
    float l2 = g0.z + bf2f(s0.z), l3 = g0.w + bf2f(s0.w);
    float l4 = g1.x + bf2f(s1.x), l5 = g1.y + bf2f(s1.y);
    float l6 = g1.z + bf2f(s1.z), l7 = g1.w + bf2f(s1.w);
    float m = fmaxf(fmaxf(fmaxf(l0, l1), fmaxf(l2, l3)),
                    fmaxf(fmaxf(l4, l5), fmaxf(l6, l7)));
#pragma unroll
    for (int o = 32; o > 0; o >>= 1) m = fmaxf(m, __shfl_xor(m, o));
    float e0 = __expf(l0 - m), e1 = __expf(l1 - m), e2 = __expf(l2 - m), e3 = __expf(l3 - m);
    float e4 = __expf(l4 - m), e5 = __expf(l5 - m), e6 = __expf(l6 - m), e7 = __expf(l7 - m);
    float s = ((e0 + e1) + (e2 + e3)) + ((e4 + e5) + (e6 + e7));
#pragma unroll
    for (int o = 32; o > 0; o >>= 1) s += __shfl_xor(s, o);
    float inv = 1.0f / s;
    ushort4 o0, o1;
    o0.x = f2bf(e0 * inv); o0.y = f2bf(e1 * inv); o0.z = f2bf(e2 * inv); o0.w = f2bf(e3 * inv);
    o1.x = f2bf(e4 * inv); o1.y = f2bf(e5 * inv); o1.z = f2bf(e6 * inv); o1.w = f2bf(e7 * inv);
    ushort4* dst = (ushort4*)(p16 + ((size_t)(b * H_ + h) * K_ + (j0 + j)) * K_);
    dst[lane] = o0;
    dst[lane + 64] = o1;
  }
}

// ---------------- K5: PV GEMM + epilogue (XCD-swizzled)  out = gamma*(attn·v)+f_a ----------------
// grid 256. xcd = bid&7; 4 (b,h) per XCD, 8 mt each.
__global__ __launch_bounds__(256) void pv_kernel(const unsigned short* __restrict__ p16,
                                                 const unsigned short* __restrict__ vt16,
                                                 const float* __restrict__ fa,
                                                 const float* __restrict__ gptr,
                                                 float* __restrict__ out) {
  int bid = blockIdx.x;
  int xcd = bid & 7, loc = bid >> 3;      // 32 per XCD
  int bh = ((loc >> 3) << 3) | xcd;       // 4 bh per XCD
  int mt = loc & 7;
  int b = bh >> 3, h = bh & 7;
  int lane = threadIdx.x & 63, wid = threadIdx.x >> 6;
  int lr = lane & 15, lg = lane >> 4;
  int row0 = mt * 64 + wid * 16;
  const unsigned short* A = p16 + ((size_t)bh * K_ + row0) * K_;
  const unsigned short* V = vt16 + (size_t)bh * DK_ * K_;

  f32x4 acc[6];
#pragma unroll
  for (int c = 0; c < 6; c++) acc[c] = (f32x4){0.f, 0.f, 0.f, 0.f};

  for (int kk = 0; kk < 16; kk++) {
    bf16x8 a = *(const bf16x8*)(A + (size_t)lr * K_ + kk * 32 + lg * 8);
#pragma unroll
    for (int c = 0; c < 6; c++) {
      bf16x8 bfr = *(const bf16x8*)(V + (size_t)(c * 16 + lr) * K_ + kk * 32 + lg * 8);
      acc[c] = __builtin_amdgcn_mfma_f32_16x16x32_bf16(a, bfr, acc[c], 0, 0, 0);
    }
  }

  float gamma = gptr[0];
#pragma unroll
  for (int c = 0; c < 6; c++) {
    int fcol = c * 16 + lr;
#pragma unroll
    for (int r = 0; r < 4; r++) {
      int j = row0 + lg * 4 + r;
      size_t oidx = ((size_t)(b * K_ + j)) * D_ + h * DK_ + fcol;
      out[oidx] = gamma * acc[c][r] + fa[oidx];
    }
  }
}

extern "C" void kernel_launch(void* const* d_in, const int* in_sizes, int n_in,
                              void* d_out, int out_size, void* d_ws, size_t ws_size,
                              hipStream_t stream) {
  (void)in_sizes; (void)n_in; (void)out_size; (void)ws_size;
  const float* fa   = (const float*)d_in[0];
  const float* pe   = (const float*)d_in[1];
  const float* wgw  = (const float*)d_in[2];
  const float* wgb  = (const float*)d_in[3];
  const float* wkw  = (const float*)d_in[4];
  const float* wkb  = (const float*)d_in[5];
  const float* wqw  = (const float*)d_in[6];
  const float* wqb  = (const float*)d_in[7];
  const float* wvw  = (const float*)d_in[8];
  const float* wvb  = (const float*)d_in[9];
  const float* gptr = (const float*)d_in[10];
  float* out = (float*)d_out;

  char* ws = (char*)d_ws;
  unsigned short* fa16 = (unsigned short*)ws; ws += (size_t)B_ * K_ * D_ * 2;
  unsigned short* wt16 = (unsigned short*)ws; ws += (size_t)3 * H_ * DK_ * D_ * 2;
  unsigned short* q16  = (unsigned short*)ws; ws += (size_t)B_ * H_ * K_ * DK_ * 2;
  unsigned short* k16  = (unsigned short*)ws; ws += (size_t)B_ * H_ * K_ * DK_ * 2;
  unsigned short* vt16 = (unsigned short*)ws; ws += (size_t)B_ * H_ * DK_ * K_ * 2;
  unsigned short* L16  = (unsigned short*)ws; ws += (size_t)B_ * H_ * K_ * K_ * 2;
  unsigned short* p16  = (unsigned short*)ws;

  const int lds_bytes = 32 * GS_PAD * 4;  // 66048 B > 64KB default -> opt in
  hipFuncSetAttribute((const void*)gatesm_kernel,
                      hipFuncAttributeMaxDynamicSharedMemorySize, lds_bytes);

  prep_kernel<<<1536 + 144, 256, 0, stream>>>(fa, fa16, wqw, wkw, wvw, wt16);
  proj_kernel<<<384, 256, 0, stream>>>(fa16, wt16, wqb, wkb, wvb, q16, k16, vt16);
  scores_kernel<<<512, 256, 0, stream>>>(q16, k16, L16);
  gatesm_kernel<<<B_ * 128, 512, lds_bytes, stream>>>(pe, wgw, wgb, L16, p16);
  pv_kernel<<<256, 256, 0, stream>>>(p16, vt16, fa, gptr, out);
}

// Round 21
// 160.144 us; speedup vs baseline: 1.2886x; 1.1331x over previous
//
#include <hip/hip_runtime.h>
#include <hip/hip_bf16.h>

#define B_ 4
#define K_ 512
#define D_ 768
#define DK_ 96
#define DG_ 96
#define H_ 8

typedef __attribute__((ext_vector_type(8))) __bf16 bf16x8;
typedef __attribute__((ext_vector_type(4))) float f32x4;

static __device__ __forceinline__ unsigned short f2bf(float x) {
  union { float f; unsigned int u; } v; v.f = x;
  unsigned int u = v.u;
  return (unsigned short)((u + 0x7FFFu + ((u >> 16) & 1u)) >> 16);
}
static __device__ __forceinline__ float bf2f(unsigned short u) {
  union { unsigned int u; float f; } v; v.u = ((unsigned int)u) << 16;
  return v.f;
}

// ---------------- K0: fused cast f_a -> FRAGMENT-MAJOR bf16  +  W -> FRAGMENT-MAJOR bf16 ----
// Fragment-major: F[rowblk][kk][lane][8] (1KB per 16row x 32col tile) so a wave's
// MFMA fragment load is 64 lanes x contiguous 16B (8 cache lines, coalesced).
// blocks [0,768): cast fa; thread = one lane-slot (8 elems). blocks [768,912): W.
__global__ __launch_bounds__(256) void prep_kernel(const float* __restrict__ fa,
                                                   unsigned short* __restrict__ fa16f,
                                                   const float* __restrict__ wq,
                                                   const float* __restrict__ wk,
                                                   const float* __restrict__ wv,
                                                   unsigned short* __restrict__ wt16f) {
  __shared__ unsigned short Ts[96][130];
  if (blockIdx.x < 768) {
    int idx = blockIdx.x * 256 + threadIdx.x;   // 196608 = B*K*D/8 lane-slots
    int row = idx / 96;                          // global row in [0, B*K)
    int d0  = (idx % 96) * 8;
    int rowblk = row >> 4, lr = row & 15;
    int kk = d0 >> 5, lg = (d0 >> 3) & 3;
    const float4* src = (const float4*)(fa + (size_t)row * D_ + d0);
    float4 v0 = src[0], v1 = src[1];
    ushort4 o0, o1;
    o0.x = f2bf(v0.x); o0.y = f2bf(v0.y); o0.z = f2bf(v0.z); o0.w = f2bf(v0.w);
    o1.x = f2bf(v1.x); o1.y = f2bf(v1.y); o1.z = f2bf(v1.z); o1.w = f2bf(v1.w);
    unsigned short* dst = fa16f + (((size_t)rowblk * 24 + kk) * 64 + lg * 16 + lr) * 8;
    ((ushort4*)dst)[0] = o0;
    ((ushort4*)dst)[1] = o1;
  } else {
    int bid = blockIdx.x - 768;                 // 144 blocks: p(3)*h(8)*dt(6)
    int dt = bid % 6; int rest = bid / 6;
    int h = rest % 8; int p = rest / 8;
    int ph = p * 8 + h;
    const float* w = (p == 0) ? wq : (p == 1) ? wk : wv;
    const float* src = w + ((size_t)h * D_ + dt * 128) * DK_;  // 128 d x 96 f, coalesced
    for (int c = threadIdx.x; c < 128 * 96; c += 256) {
      int dd = c / 96, f = c % 96;
      Ts[f][dd] = f2bf(src[c]);
    }
    __syncthreads();
    // write fragment-major: wt16f[ph][cfrag(6)][kk(24)][lane][8]
    for (int c = threadIdx.x; c < 96 * 32; c += 256) {   // 32 ushort4 per f-row
      int f = c / 32, q = c % 32;                        // d_local = q*4
      int kk = dt * 4 + (q >> 3);
      int lg = (q >> 1) & 3;
      int e  = (q & 1) * 4;
      ushort4 v;
      v.x = Ts[f][q * 4 + 0]; v.y = Ts[f][q * 4 + 1];
      v.z = Ts[f][q * 4 + 2]; v.w = Ts[f][q * 4 + 3];
      unsigned short* dst = wt16f +
          ((((size_t)ph * 6 + (f >> 4)) * 24 + kk) * 64 + lg * 16 + (f & 15)) * 8 + e;
      *(ushort4*)dst = v;
    }
  }
}

// ---------------- K1: projections (fragment-major operands, coalesced frag loads) ----------------
// grid 384, XCD-swizzled. Every A/B fragment load = 64 lanes x contiguous 16B.
// p==2 (V) transposes its 128x96 output tile through LDS -> vt16 directly.
__global__ __launch_bounds__(256) void proj_kernel(
    const unsigned short* __restrict__ fa16f, const unsigned short* __restrict__ wt16f,
    const float* __restrict__ bq, const float* __restrict__ bk, const float* __restrict__ bv,
    unsigned short* __restrict__ q16, unsigned short* __restrict__ k16,
    unsigned short* __restrict__ vt16) {
  __shared__ unsigned short Ts[96][130];   // used only by p==2 epilogue
  int bid = blockIdx.x;
  int xcd = bid & 7, loc = bid >> 3;  // XCD-aware mapping (bijective over 384)
  int b = xcd >> 1, half = xcd & 1;
  int ph = half * 12 + (loc >> 2);    // 12 panels per XCD
  int mt = loc & 3;
  int p = ph >> 3, h = ph & 7;
  int lane = threadIdx.x & 63, wid = threadIdx.x >> 6;
  int lr = lane & 15, lg = lane >> 4;
  int row0 = mt * 128 + wid * 32;     // wave owns 32 rows (2 m-frags)
  int rb0 = b * 32 + mt * 8 + wid * 2;  // global rowblk of frag 0

  const unsigned short* A  = fa16f + ((size_t)rb0 * 24) * 512 + lane * 8;
  const unsigned short* Bt = wt16f + ((size_t)ph * 6 * 24) * 512 + lane * 8;

  f32x4 acc[2][6];
#pragma unroll
  for (int i = 0; i < 2; i++)
#pragma unroll
    for (int c = 0; c < 6; c++) acc[i][c] = (f32x4){0.f, 0.f, 0.f, 0.f};

  auto LOADF = [&](bf16x8& a0, bf16x8& a1, bf16x8 (&bb)[6], int kk) {
    a0 = *(const bf16x8*)(A + (size_t)kk * 512);             // frag (rb0, kk)
    a1 = *(const bf16x8*)(A + ((size_t)24 + kk) * 512);      // frag (rb0+1, kk)
#pragma unroll
    for (int c = 0; c < 6; c++)
      bb[c] = *(const bf16x8*)(Bt + ((size_t)c * 24 + kk) * 512);
  };
  auto MF = [&](bf16x8& a0, bf16x8& a1, bf16x8 (&bb)[6]) {
#pragma unroll
    for (int c = 0; c < 6; c++) {
      acc[0][c] = __builtin_amdgcn_mfma_f32_16x16x32_bf16(a0, bb[c], acc[0][c], 0, 0, 0);
      acc[1][c] = __builtin_amdgcn_mfma_f32_16x16x32_bf16(a1, bb[c], acc[1][c], 0, 0, 0);
    }
  };

  bf16x8 a0X, a1X, bX[6], a0Y, a1Y, bY[6];
  LOADF(a0X, a1X, bX, 0);
  for (int kk = 0; kk < 24; kk += 2) {          // 24 K-steps, ping-pong
    LOADF(a0Y, a1Y, bY, kk + 1);
    MF(a0X, a1X, bX);
    if (kk + 2 < 24) LOADF(a0X, a1X, bX, kk + 2);
    MF(a0Y, a1Y, bY);
  }

  const float* bias = (p == 0) ? bq : (p == 1) ? bk : bv;
  if (p == 2) {
    // V: transpose 128x96 tile through LDS, write vt16 [bh][f][i] coalesced
#pragma unroll
    for (int i = 0; i < 2; i++)
#pragma unroll
      for (int c = 0; c < 6; c++) {
        int col = c * 16 + lr;
        float bb = bias[h * DK_ + col];
#pragma unroll
        for (int r = 0; r < 4; r++) {
          int lrow = wid * 32 + i * 16 + lg * 4 + r;
          Ts[col][lrow] = f2bf(acc[i][c][r] + bb);
        }
      }
    __syncthreads();
    unsigned short* dst = vt16 + (size_t)(b * H_ + h) * DK_ * K_ + mt * 128;
    for (int c2 = threadIdx.x; c2 < 96 * 32; c2 += 256) {
      int f = c2 / 32, q = c2 % 32;
      ushort4 v;
      v.x = Ts[f][q * 4 + 0]; v.y = Ts[f][q * 4 + 1];
      v.z = Ts[f][q * 4 + 2]; v.w = Ts[f][q * 4 + 3];
      *(ushort4*)(dst + (size_t)f * K_ + q * 4) = v;
    }
  } else {
    unsigned short* dst = (p == 0) ? q16 : k16;
#pragma unroll
    for (int i = 0; i < 2; i++)
#pragma unroll
      for (int c = 0; c < 6; c++) {
        int col = c * 16 + lr;
        float bb = bias[h * DK_ + col];
#pragma unroll
        for (int r = 0; r < 4; r++) {
          int row = row0 + i * 16 + lg * 4 + r;
          dst[((size_t)(b * H_ + h) * K_ + row) * DK_ + col] = f2bf(acc[i][c][r] + bb);
        }
      }
  }
}

// ---------------- K2: scores L16[b][h][j][i] = bf16(q[j]·k[i]/sqrt(96))  (XCD-swizzled) ----------------
// grid 512. xcd = bid&7; 4 (b,h) pairs per XCD, 16 tiles each. bf16 store halves L traffic.
__global__ __launch_bounds__(256) void scores_kernel(const unsigned short* __restrict__ q16,
                                                     const unsigned short* __restrict__ k16,
                                                     unsigned short* __restrict__ L16) {
  int bid = blockIdx.x;
  int xcd = bid & 7, loc = bid >> 3;      // 64 per XCD
  int bh = ((loc >> 4) << 3) | xcd;       // 4 bh per XCD
  int jt = (loc >> 2) & 3, it = loc & 3;
  int b = bh >> 3, h = bh & 7;
  int lane = threadIdx.x & 63, wid = threadIdx.x >> 6;
  int lr = lane & 15, lg = lane >> 4;
  int j0 = jt * 128 + wid * 32;
  int i0 = it * 128;
  const unsigned short* Q  = q16 + ((size_t)(b * H_ + h) * K_ + j0) * DK_;
  const unsigned short* Kp = k16 + ((size_t)(b * H_ + h) * K_ + i0) * DK_;

  f32x4 acc[2][8];
#pragma unroll
  for (int x = 0; x < 2; x++)
#pragma unroll
    for (int c = 0; c < 8; c++) acc[x][c] = (f32x4){0.f, 0.f, 0.f, 0.f};

#pragma unroll
  for (int kk = 0; kk < 3; kk++) {
    bf16x8 a0 = *(const bf16x8*)(Q + (size_t)lr * DK_ + kk * 32 + lg * 8);
    bf16x8 a1 = *(const bf16x8*)(Q + (size_t)(16 + lr) * DK_ + kk * 32 + lg * 8);
#pragma unroll
    for (int c = 0; c < 8; c++) {
      bf16x8 bfr = *(const bf16x8*)(Kp + (size_t)(c * 16 + lr) * DK_ + kk * 32 + lg * 8);
      acc[0][c] = __builtin_amdgcn_mfma_f32_16x16x32_bf16(a0, bfr, acc[0][c], 0, 0, 0);
      acc[1][c] = __builtin_amdgcn_mfma_f32_16x16x32_bf16(a1, bfr, acc[1][c], 0, 0, 0);
    }
  }

  const float scale = 0.10206207261596577f;  // 1/sqrt(96)
  unsigned short* Lb = L16 + ((size_t)(b * H_ + h) * K_ + j0) * K_ + i0;
#pragma unroll
  for (int x = 0; x < 2; x++)
#pragma unroll
    for (int c = 0; c < 8; c++)
#pragma unroll
      for (int r = 0; r < 4; r++) {
        int jl = x * 16 + lg * 4 + r;
        int il = c * 16 + lr;
        Lb[(size_t)jl * K_ + il] = f2bf(acc[x][c][r] * scale);
      }
}

// ---------------- K3: fused gate + softmax (R4 structure; L read as bf16) ----------------
// grid: b(4) * jslab(128), jslab = 4 j-columns; 512 threads.
// Phase A: 8 lanes cooperate per pe row (lane&7 = g-chunk) -> 16 lines/instr.
// LDS: gate-logits [32 rows][516 pad] fp32 = 66 KB -> 2 blocks/CU.
#define GS_PAD 516
__global__ __launch_bounds__(512) void gatesm_kernel(
    const float* __restrict__ pe, const float* __restrict__ wgw,
    const float* __restrict__ wgb, const unsigned short* __restrict__ L16,
    unsigned short* __restrict__ p16) {
  extern __shared__ float Ls[];
  int b = blockIdx.x >> 7;
  int j0 = (blockIdx.x & 127) * 4;
  int t = threadIdx.x;
  int wv = t >> 6, lane = t & 63;
  int lr3 = (lane >> 3) & 7;   // row-in-pass
  int lg3 = lane & 7;          // g-chunk (of 24 float4 chunks, this lane does lg3, lg3+8, lg3+16)
  const float4* pe4 = (const float4*)pe;
  const float4* wg4 = (const float4*)wgw;

  // --- Phase A: gate logits -> LDS ---
  for (int p = 0; p < 8; p++) {
    int i = wv * 64 + p * 8 + lr3;
    float4 pev[4][3];
#pragma unroll
    for (int j = 0; j < 4; j++) {
      size_t base = ((size_t)(b * K_ + i) * K_ + (j0 + j)) * (DG_ / 4);
#pragma unroll
      for (int c = 0; c < 3; c++) pev[j][c] = pe4[base + lg3 + 8 * c];
    }
#pragma unroll
    for (int h = 0; h < H_; h++) {
      float4 w0 = wg4[h * 24 + lg3];
      float4 w1 = wg4[h * 24 + lg3 + 8];
      float4 w2 = wg4[h * 24 + lg3 + 16];
      float bias = wgb[h];
      float acc[4];
#pragma unroll
      for (int j = 0; j < 4; j++) {
        acc[j] = pev[j][0].x * w0.x + pev[j][0].y * w0.y + pev[j][0].z * w0.z + pev[j][0].w * w0.w
               + pev[j][1].x * w1.x + pev[j][1].y * w1.y + pev[j][1].z * w1.z + pev[j][1].w * w1.w
               + pev[j][2].x * w2.x + pev[j][2].y * w2.y + pev[j][2].z * w2.z + pev[j][2].w * w2.w;
      }
#pragma unroll
      for (int j = 0; j < 4; j++) {
        acc[j] += __shfl_xor(acc[j], 1);
        acc[j] += __shfl_xor(acc[j], 2);
        acc[j] += __shfl_xor(acc[j], 4);
      }
      if (lg3 == h) {   // h is a literal per unrolled iteration -> static predication
#pragma unroll
        for (int j = 0; j < 4; j++) {
          float lgt = __logf(fmaxf(acc[j] + bias, 1e-6f));  // relu+clip == max(.,1e-6)
          Ls[(h * 4 + j) * GS_PAD + i] = lgt;
        }
      }
    }
  }
  __syncthreads();

  // --- Phase B: logits = LDS gate + bf16 global scores; softmax over i; write p16 ---
#pragma unroll
  for (int rr = 0; rr < 4; rr++) {
    int row = wv * 4 + rr;          // 32 rows = (h, j)
    int h = row >> 2, j = row & 3;
    const float* Lr = &Ls[row * GS_PAD];
    const unsigned short* Lg = L16 + ((size_t)(b * H_ + h) * K_ + (j0 + j)) * K_;
    float4 g0 = *(const float4*)(Lr + lane * 4);
    float4 g1 = *(const float4*)(Lr + 256 + lane * 4);
    ushort4 s0 = *(const ushort4*)(Lg + lane * 4);
    ushort4 s1 = *(const ushort4*)(Lg + 256 + lane * 4);
    float l0 = g0.x + bf2f(s0.x), l1 = g0.y + bf2f(s0.y);
    float l2 = g0.z + bf2f(s0.z), l3 = g0.w + bf2f(s0.w);
    float l4 = g1.x + bf2f(s1.x), l5 = g1.y + bf2f(s1.y);
    float l6 = g1.z + bf2f(s1.z), l7 = g1.w + bf2f(s1.w);
    float m = fmaxf(fmaxf(fmaxf(l0, l1), fmaxf(l2, l3)),
                    fmaxf(fmaxf(l4, l5), fmaxf(l6, l7)));
#pragma unroll
    for (int o = 32; o > 0; o >>= 1) m = fmaxf(m, __shfl_xor(m, o));
    float e0 = __expf(l0 - m), e1 = __expf(l1 - m), e2 = __expf(l2 - m), e3 = __expf(l3 - m);
    float e4 = __expf(l4 - m), e5 = __expf(l5 - m), e6 = __expf(l6 - m), e7 = __expf(l7 - m);
    float s = ((e0 + e1) + (e2 + e3)) + ((e4 + e5) + (e6 + e7));
#pragma unroll
    for (int o = 32; o > 0; o >>= 1) s += __shfl_xor(s, o);
    float inv = 1.0f / s;
    ushort4 o0, o1;
    o0.x = f2bf(e0 * inv); o0.y = f2bf(e1 * inv); o0.z = f2bf(e2 * inv); o0.w = f2bf(e3 * inv);
    o1.x = f2bf(e4 * inv); o1.y = f2bf(e5 * inv); o1.z = f2bf(e6 * inv); o1.w = f2bf(e7 * inv);
    ushort4* dst = (ushort4*)(p16 + ((size_t)(b * H_ + h) * K_ + (j0 + j)) * K_);
    dst[lane] = o0;
    dst[lane + 64] = o1;
  }
}

// ---------------- K5: PV GEMM + epilogue (XCD-swizzled)  out = gamma*(attn·v)+f_a ----------------
// grid 256. xcd = bid&7; 4 (b,h) per XCD, 8 mt each.
__global__ __launch_bounds__(256) void pv_kernel(const unsigned short* __restrict__ p16,
                                                 const unsigned short* __restrict__ vt16,
                                                 const float* __restrict__ fa,
                                                 const float* __restrict__ gptr,
                                                 float* __restrict__ out) {
  int bid = blockIdx.x;
  int xcd = bid & 7, loc = bid >> 3;      // 32 per XCD
  int bh = ((loc >> 3) << 3) | xcd;       // 4 bh per XCD
  int mt = loc & 7;
  int b = bh >> 3, h = bh & 7;
  int lane = threadIdx.x & 63, wid = threadIdx.x >> 6;
  int lr = lane & 15, lg = lane >> 4;
  int row0 = mt * 64 + wid * 16;
  const unsigned short* A = p16 + ((size_t)bh * K_ + row0) * K_;
  const unsigned short* V = vt16 + (size_t)bh * DK_ * K_;

  f32x4 acc[6];
#pragma unroll
  for (int c = 0; c < 6; c++) acc[c] = (f32x4){0.f, 0.f, 0.f, 0.f};

  for (int kk = 0; kk < 16; kk++) {
    bf16x8 a = *(const bf16x8*)(A + (size_t)lr * K_ + kk * 32 + lg * 8);
#pragma unroll
    for (int c = 0; c < 6; c++) {
      bf16x8 bfr = *(const bf16x8*)(V + (size_t)(c * 16 + lr) * K_ + kk * 32 + lg * 8);
      acc[c] = __builtin_amdgcn_mfma_f32_16x16x32_bf16(a, bfr, acc[c], 0, 0, 0);
    }
  }

  float gamma = gptr[0];
#pragma unroll
  for (int c = 0; c < 6; c++) {
    int fcol = c * 16 + lr;
#pragma unroll
    for (int r = 0; r < 4; r++) {
      int j = row0 + lg * 4 + r;
      size_t oidx = ((size_t)(b * K_ + j)) * D_ + h * DK_ + fcol;
      out[oidx] = gamma * acc[c][r] + fa[oidx];
    }
  }
}

extern "C" void kernel_launch(void* const* d_in, const int* in_sizes, int n_in,
                              void* d_out, int out_size, void* d_ws, size_t ws_size,
                              hipStream_t stream) {
  (void)in_sizes; (void)n_in; (void)out_size; (void)ws_size;
  const float* fa   = (const float*)d_in[0];
  const float* pe   = (const float*)d_in[1];
  const float* wgw  = (const float*)d_in[2];
  const float* wgb  = (const float*)d_in[3];
  const float* wkw  = (const float*)d_in[4];
  const float* wkb  = (const float*)d_in[5];
  const float* wqw  = (const float*)d_in[6];
  const float* wqb  = (const float*)d_in[7];
  const float* wvw  = (const float*)d_in[8];
  const float* wvb  = (const float*)d_in[9];
  const float* gptr = (const float*)d_in[10];
  float* out = (float*)d_out;

  char* ws = (char*)d_ws;
  unsigned short* fa16f = (unsigned short*)ws; ws += (size_t)B_ * K_ * D_ * 2;
  unsigned short* wt16f = (unsigned short*)ws; ws += (size_t)3 * H_ * DK_ * D_ * 2;
  unsigned short* q16   = (unsigned short*)ws; ws += (size_t)B_ * H_ * K_ * DK_ * 2;
  unsigned short* k16   = (unsigned short*)ws; ws += (size_t)B_ * H_ * K_ * DK_ * 2;
  unsigned short* vt16  = (unsigned short*)ws; ws += (size_t)B_ * H_ * DK_ * K_ * 2;
  unsigned short* L16   = (unsigned short*)ws; ws += (size_t)B_ * H_ * K_ * K_ * 2;
  unsigned short* p16   = (unsigned short*)ws;

  const int lds_bytes = 32 * GS_PAD * 4;  // 66048 B > 64KB default -> opt in
  hipFuncSetAttribute((const void*)gatesm_kernel,
                      hipFuncAttributeMaxDynamicSharedMemorySize, lds_bytes);

  prep_kernel<<<768 + 144, 256, 0, stream>>>(fa, fa16f, wqw, wkw, wvw, wt16f);
  proj_kernel<<<384, 256, 0, stream>>>(fa16f, wt16f, wqb, wkb, wvb, q16, k16, vt16);
  scores_kernel<<<512, 256, 0, stream>>>(q16, k16, L16);
  gatesm_kernel<<<B_ * 128, 512, lds_bytes, stream>>>(pe, wgw, wgb, L16, p16);
  pv_kernel<<<256, 256, 0, stream>>>(p16, vt16, fa, gptr, out);
}

// Round 22
// 154.598 us; speedup vs baseline: 1.3348x; 1.0359x over previous
//
#include <hip/hip_runtime.h>
#include <hip/hip_bf16.h>

#define B_ 4
#define K_ 512
#define D_ 768
#define DK_ 96
#define DG_ 96
#define H_ 8

typedef __attribute__((ext_vector_type(8))) __bf16 bf16x8;
typedef __attribute__((ext_vector_type(4))) float f32x4;

static __device__ __forceinline__ unsigned short f2bf(float x) {
  union { float f; unsigned int u; } v; v.f = x;
  unsigned int u = v.u;
  return (unsigned short)((u + 0x7FFFu + ((u >> 16) & 1u)) >> 16);
}
static __device__ __forceinline__ float bf2f(unsigned short u) {
  union { unsigned int u; float f; } v; v.u = ((unsigned int)u) << 16;
  return v.f;
}

// ---------------- K0: fused cast f_a -> FRAGMENT-MAJOR bf16  +  W -> FRAGMENT-MAJOR bf16 ----
// Fragment-major: F[rowblk][kk][lane][8] so a wave's MFMA fragment load is
// 64 lanes x contiguous 16B (8 cache lines, coalesced).
__global__ __launch_bounds__(256) void prep_kernel(const float* __restrict__ fa,
                                                   unsigned short* __restrict__ fa16f,
                                                   const float* __restrict__ wq,
                                                   const float* __restrict__ wk,
                                                   const float* __restrict__ wv,
                                                   unsigned short* __restrict__ wt16f) {
  __shared__ unsigned short Ts[96][130];
  if (blockIdx.x < 768) {
    int idx = blockIdx.x * 256 + threadIdx.x;   // 196608 = B*K*D/8 lane-slots
    int row = idx / 96;                          // global row in [0, B*K)
    int d0  = (idx % 96) * 8;
    int rowblk = row >> 4, lr = row & 15;
    int kk = d0 >> 5, lg = (d0 >> 3) & 3;
    const float4* src = (const float4*)(fa + (size_t)row * D_ + d0);
    float4 v0 = src[0], v1 = src[1];
    ushort4 o0, o1;
    o0.x = f2bf(v0.x); o0.y = f2bf(v0.y); o0.z = f2bf(v0.z); o0.w = f2bf(v0.w);
    o1.x = f2bf(v1.x); o1.y = f2bf(v1.y); o1.z = f2bf(v1.z); o1.w = f2bf(v1.w);
    unsigned short* dst = fa16f + (((size_t)rowblk * 24 + kk) * 64 + lg * 16 + lr) * 8;
    ((ushort4*)dst)[0] = o0;
    ((ushort4*)dst)[1] = o1;
  } else {
    int bid = blockIdx.x - 768;                 // 144 blocks: p(3)*h(8)*dt(6)
    int dt = bid % 6; int rest = bid / 6;
    int h = rest % 8; int p = rest / 8;
    int ph = p * 8 + h;
    const float* w = (p == 0) ? wq : (p == 1) ? wk : wv;
    const float* src = w + ((size_t)h * D_ + dt * 128) * DK_;  // 128 d x 96 f, coalesced
    for (int c = threadIdx.x; c < 128 * 96; c += 256) {
      int dd = c / 96, f = c % 96;
      Ts[f][dd] = f2bf(src[c]);
    }
    __syncthreads();
    // write fragment-major: wt16f[ph][cfrag(6)][kk(24)][lane][8]
    for (int c = threadIdx.x; c < 96 * 32; c += 256) {   // 32 ushort4 per f-row
      int f = c / 32, q = c % 32;                        // d_local = q*4
      int kk = dt * 4 + (q >> 3);
      int lg = (q >> 1) & 3;
      int e  = (q & 1) * 4;
      ushort4 v;
      v.x = Ts[f][q * 4 + 0]; v.y = Ts[f][q * 4 + 1];
      v.z = Ts[f][q * 4 + 2]; v.w = Ts[f][q * 4 + 3];
      unsigned short* dst = wt16f +
          ((((size_t)ph * 6 + (f >> 4)) * 24 + kk) * 64 + lg * 16 + (f & 15)) * 8 + e;
      *(ushort4*)dst = v;
    }
  }
}

// ---------------- K1: projections (fragment-major in AND out) ----------------
// grid 384, XCD-swizzled. Every A/B fragment load = 64 lanes x contiguous 16B.
// Q/K outputs written fragment-major [bh][rowblk(32)][kk(3)][lane][8] for scores.
// V (p==2) transposes its tile through LDS -> vt16f [bh][fblk(6)][kk(16)][lane][8] for pv.
__global__ __launch_bounds__(256) void proj_kernel(
    const unsigned short* __restrict__ fa16f, const unsigned short* __restrict__ wt16f,
    const float* __restrict__ bq, const float* __restrict__ bk, const float* __restrict__ bv,
    unsigned short* __restrict__ q16f, unsigned short* __restrict__ k16f,
    unsigned short* __restrict__ vt16f) {
  __shared__ unsigned short Ts[96][132];   // used only by p==2 epilogue (stride 132 for 8B align)
  int bid = blockIdx.x;
  int xcd = bid & 7, loc = bid >> 3;  // XCD-aware mapping (bijective over 384)
  int b = xcd >> 1, half = xcd & 1;
  int ph = half * 12 + (loc >> 2);    // 12 panels per XCD
  int mt = loc & 3;
  int p = ph >> 3, h = ph & 7;
  int lane = threadIdx.x & 63, wid = threadIdx.x >> 6;
  int lr = lane & 15, lg = lane >> 4;
  int rb0 = b * 32 + mt * 8 + wid * 2;  // global rowblk of frag 0

  const unsigned short* A  = fa16f + ((size_t)rb0 * 24) * 512 + lane * 8;
  const unsigned short* Bt = wt16f + ((size_t)ph * 6 * 24) * 512 + lane * 8;

  f32x4 acc[2][6];
#pragma unroll
  for (int i = 0; i < 2; i++)
#pragma unroll
    for (int c = 0; c < 6; c++) acc[i][c] = (f32x4){0.f, 0.f, 0.f, 0.f};

  auto LOADF = [&](bf16x8& a0, bf16x8& a1, bf16x8 (&bb)[6], int kk) {
    a0 = *(const bf16x8*)(A + (size_t)kk * 512);             // frag (rb0, kk)
    a1 = *(const bf16x8*)(A + ((size_t)24 + kk) * 512);      // frag (rb0+1, kk)
#pragma unroll
    for (int c = 0; c < 6; c++)
      bb[c] = *(const bf16x8*)(Bt + ((size_t)c * 24 + kk) * 512);
  };
  auto MF = [&](bf16x8& a0, bf16x8& a1, bf16x8 (&bb)[6]) {
#pragma unroll
    for (int c = 0; c < 6; c++) {
      acc[0][c] = __builtin_amdgcn_mfma_f32_16x16x32_bf16(a0, bb[c], acc[0][c], 0, 0, 0);
      acc[1][c] = __builtin_amdgcn_mfma_f32_16x16x32_bf16(a1, bb[c], acc[1][c], 0, 0, 0);
    }
  };

  bf16x8 a0X, a1X, bX[6], a0Y, a1Y, bY[6];
  LOADF(a0X, a1X, bX, 0);
  for (int kk = 0; kk < 24; kk += 2) {          // 24 K-steps, ping-pong
    LOADF(a0Y, a1Y, bY, kk + 1);
    MF(a0X, a1X, bX);
    if (kk + 2 < 24) LOADF(a0X, a1X, bX, kk + 2);
    MF(a0Y, a1Y, bY);
  }

  const float* bias = (p == 0) ? bq : (p == 1) ? bk : bv;
  if (p == 2) {
    // V: stage 128x96 tile in LDS, write vt16f fragment-major (coalesced 16B/lane)
#pragma unroll
    for (int i = 0; i < 2; i++)
#pragma unroll
      for (int c = 0; c < 6; c++) {
        int col = c * 16 + lr;
        float bb = bias[h * DK_ + col];
#pragma unroll
        for (int r = 0; r < 4; r++) {
          int lrow = wid * 32 + i * 16 + lg * 4 + r;
          Ts[col][lrow] = f2bf(acc[i][c][r] + bb);
        }
      }
    __syncthreads();
    unsigned short* dst = vt16f + (size_t)(b * H_ + h) * 49152;
    for (int c2 = threadIdx.x; c2 < 1536; c2 += 256) {  // 6 fblk * 4 kkl * 64 lane-slots
      int lane_d = c2 & 63;
      int kkl = (c2 >> 6) & 3;
      int fblk = c2 >> 8;
      int f = fblk * 16 + (lane_d & 15);
      int il = kkl * 32 + (lane_d >> 4) * 8;
      ushort4 v0 = *(const ushort4*)&Ts[f][il];
      ushort4 v1 = *(const ushort4*)&Ts[f][il + 4];
      unsigned short* o = dst + (((size_t)fblk * 16 + (mt * 4 + kkl)) * 64 + lane_d) * 8;
      ((ushort4*)o)[0] = v0;
      ((ushort4*)o)[1] = v1;
    }
  } else {
    // Q/K: fragment-major writes for scores' coalesced frag loads
    unsigned short* dst = ((p == 0) ? q16f : k16f) + (size_t)(b * H_ + h) * 49152;
#pragma unroll
    for (int i = 0; i < 2; i++) {
      int rowblk = mt * 8 + wid * 2 + i;
#pragma unroll
      for (int c = 0; c < 6; c++) {
        int col = c * 16 + lr;
        int kk = col >> 5, klg = (col >> 3) & 3, e = col & 7;
        float bb = bias[h * DK_ + col];
#pragma unroll
        for (int r = 0; r < 4; r++) {
          int row_lr = lg * 4 + r;
          dst[(((size_t)rowblk * 3 + kk) * 64 + klg * 16 + row_lr) * 8 + e] =
              f2bf(acc[i][c][r] + bb);
        }
      }
    }
  }
}

// ---------------- K2: scores (fragment-major Q/K loads)  L16 = bf16(q·k/sqrt(96)) ----------------
// grid 512, XCD-swizzled. All frag loads = 64 lanes x contiguous 16B.
__global__ __launch_bounds__(256) void scores_kernel(const unsigned short* __restrict__ q16f,
                                                     const unsigned short* __restrict__ k16f,
                                                     unsigned short* __restrict__ L16) {
  int bid = blockIdx.x;
  int xcd = bid & 7, loc = bid >> 3;      // 64 per XCD
  int bh = ((loc >> 4) << 3) | xcd;       // 4 bh per XCD
  int jt = (loc >> 2) & 3, it = loc & 3;
  int b = bh >> 3, h = bh & 7;
  int lane = threadIdx.x & 63, wid = threadIdx.x >> 6;
  int lr = lane & 15, lg = lane >> 4;
  int j0 = jt * 128 + wid * 32;
  int i0 = it * 128;
  const unsigned short* Qf = q16f + (size_t)bh * 49152 + lane * 8;
  const unsigned short* Kf = k16f + (size_t)bh * 49152 + lane * 8;
  int jb0 = jt * 8 + wid * 2;

  f32x4 acc[2][8];
#pragma unroll
  for (int x = 0; x < 2; x++)
#pragma unroll
    for (int c = 0; c < 8; c++) acc[x][c] = (f32x4){0.f, 0.f, 0.f, 0.f};

#pragma unroll
  for (int kk = 0; kk < 3; kk++) {
    bf16x8 a0 = *(const bf16x8*)(Qf + ((size_t)(jb0 + 0) * 3 + kk) * 512);
    bf16x8 a1 = *(const bf16x8*)(Qf + ((size_t)(jb0 + 1) * 3 + kk) * 512);
#pragma unroll
    for (int c = 0; c < 8; c++) {
      bf16x8 bfr = *(const bf16x8*)(Kf + ((size_t)(it * 8 + c) * 3 + kk) * 512);
      acc[0][c] = __builtin_amdgcn_mfma_f32_16x16x32_bf16(a0, bfr, acc[0][c], 0, 0, 0);
      acc[1][c] = __builtin_amdgcn_mfma_f32_16x16x32_bf16(a1, bfr, acc[1][c], 0, 0, 0);
    }
  }

  const float scale = 0.10206207261596577f;  // 1/sqrt(96)
  unsigned short* Lb = L16 + ((size_t)bh * K_ + j0) * K_ + i0;
#pragma unroll
  for (int x = 0; x < 2; x++)
#pragma unroll
    for (int c = 0; c < 8; c++)
#pragma unroll
      for (int r = 0; r < 4; r++) {
        int jl = x * 16 + lg * 4 + r;
        int il = c * 16 + lr;
        Lb[(size_t)jl * K_ + il] = f2bf(acc[x][c][r] * scale);
      }
}

// ---------------- K3: fused gate + softmax (R4 structure; L read as bf16) ----------------
// grid: b(4) * jslab(128), jslab = 4 j-columns; 512 threads.
// LDS: gate-logits [32 rows][516 pad] fp32 = 66 KB -> 2 blocks/CU.
#define GS_PAD 516
__global__ __launch_bounds__(512) void gatesm_kernel(
    const float* __restrict__ pe, const float* __restrict__ wgw,
    const float* __restrict__ wgb, const unsigned short* __restrict__ L16,
    unsigned short* __restrict__ p16) {
  extern __shared__ float Ls[];
  int b = blockIdx.x >> 7;
  int j0 = (blockIdx.x & 127) * 4;
  int t = threadIdx.x;
  int wv = t >> 6, lane = t & 63;
  int lr3 = (lane >> 3) & 7;   // row-in-pass
  int lg3 = lane & 7;          // g-chunk (of 24 float4 chunks, this lane does lg3, lg3+8, lg3+16)
  const float4* pe4 = (const float4*)pe;
  const float4* wg4 = (const float4*)wgw;

  // --- Phase A: gate logits -> LDS ---
  for (int p = 0; p < 8; p++) {
    int i = wv * 64 + p * 8 + lr3;
    float4 pev[4][3];
#pragma unroll
    for (int j = 0; j < 4; j++) {
      size_t base = ((size_t)(b * K_ + i) * K_ + (j0 + j)) * (DG_ / 4);
#pragma unroll
      for (int c = 0; c < 3; c++) pev[j][c] = pe4[base + lg3 + 8 * c];
    }
#pragma unroll
    for (int h = 0; h < H_; h++) {
      float4 w0 = wg4[h * 24 + lg3];
      float4 w1 = wg4[h * 24 + lg3 + 8];
      float4 w2 = wg4[h * 24 + lg3 + 16];
      float bias = wgb[h];
      float acc[4];
#pragma unroll
      for (int j = 0; j < 4; j++) {
        acc[j] = pev[j][0].x * w0.x + pev[j][0].y * w0.y + pev[j][0].z * w0.z + pev[j][0].w * w0.w
               + pev[j][1].x * w1.x + pev[j][1].y * w1.y + pev[j][1].z * w1.z + pev[j][1].w * w1.w
               + pev[j][2].x * w2.x + pev[j][2].y * w2.y + pev[j][2].z * w2.z + pev[j][2].w * w2.w;
      }
#pragma unroll
      for (int j = 0; j < 4; j++) {
        acc[j] += __shfl_xor(acc[j], 1);
        acc[j] += __shfl_xor(acc[j], 2);
        acc[j] += __shfl_xor(acc[j], 4);
      }
      if (lg3 == h) {   // h is a literal per unrolled iteration -> static predication
#pragma unroll
        for (int j = 0; j < 4; j++) {
          float lgt = __logf(fmaxf(acc[j] + bias, 1e-6f));  // relu+clip == max(.,1e-6)
          Ls[(h * 4 + j) * GS_PAD + i] = lgt;
        }
      }
    }
  }
  __syncthreads();

  // --- Phase B: logits = LDS gate + bf16 global scores; softmax over i; write p16 ---
#pragma unroll
  for (int rr = 0; rr < 4; rr++) {
    int row = wv * 4 + rr;          // 32 rows = (h, j)
    int h = row >> 2, j = row & 3;
    const float* Lr = &Ls[row * GS_PAD];
    const unsigned short* Lg = L16 + ((size_t)(b * H_ + h) * K_ + (j0 + j)) * K_;
    float4 g0 = *(const float4*)(Lr + lane * 4);
    float4 g1 = *(const float4*)(Lr + 256 + lane * 4);
    ushort4 s0 = *(const ushort4*)(Lg + lane * 4);
    ushort4 s1 = *(const ushort4*)(Lg + 256 + lane * 4);
    float l0 = g0.x + bf2f(s0.x), l1 = g0.y + bf2f(s0.y);
    float l2 = g0.z + bf2f(s0.z), l3 = g0.w + bf2f(s0.w);
    float l4 = g1.x + bf2f(s1.x), l5 = g1.y + bf2f(s1.y);
    float l6 = g1.z + bf2f(s1.z), l7 = g1.w + bf2f(s1.w);
    float m = fmaxf(fmaxf(fmaxf(l0, l1), fmaxf(l2, l3)),
                    fmaxf(fmaxf(l4, l5), fmaxf(l6, l7)));
#pragma unroll
    for (int o = 32; o > 0; o >>= 1) m = fmaxf(m, __shfl_xor(m, o));
    float e0 = __expf(l0 - m), e1 = __expf(l1 - m), e2 = __expf(l2 - m), e3 = __expf(l3 - m);
    float e4 = __expf(l4 - m), e5 = __expf(l5 - m), e6 = __expf(l6 - m), e7 = __expf(l7 - m);
    float s = ((e0 + e1) + (e2 + e3)) + ((e4 + e5) + (e6 + e7));
#pragma unroll
    for (int o = 32; o > 0; o >>= 1) s += __shfl_xor(s, o);
    float inv = 1.0f / s;
    ushort4 o0, o1;
    o0.x = f2bf(e0 * inv); o0.y = f2bf(e1 * inv); o0.z = f2bf(e2 * inv); o0.w = f2bf(e3 * inv);
    o1.x = f2bf(e4 * inv); o1.y = f2bf(e5 * inv); o1.z = f2bf(e6 * inv); o1.w = f2bf(e7 * inv);
    ushort4* dst = (ushort4*)(p16 + ((size_t)(b * H_ + h) * K_ + (j0 + j)) * K_);
    dst[lane] = o0;
    dst[lane + 64] = o1;
  }
}

// ---------------- K5: PV GEMM + epilogue (fragment-major V)  out = gamma*(attn·v)+f_a ----------------
// grid 256, XCD-swizzled. V frag loads coalesced (vt16f); A (p16) row-major.
__global__ __launch_bounds__(256) void pv_kernel(const unsigned short* __restrict__ p16,
                                                 const unsigned short* __restrict__ vt16f,
                                                 const float* __restrict__ fa,
                                                 const float* __restrict__ gptr,
                                                 float* __restrict__ out) {
  int bid = blockIdx.x;
  int xcd = bid & 7, loc = bid >> 3;      // 32 per XCD
  int bh = ((loc >> 3) << 3) | xcd;       // 4 bh per XCD
  int mt = loc & 7;
  int b = bh >> 3, h = bh & 7;
  int lane = threadIdx.x & 63, wid = threadIdx.x >> 6;
  int lr = lane & 15, lg = lane >> 4;
  int row0 = mt * 64 + wid * 16;
  const unsigned short* A  = p16 + ((size_t)bh * K_ + row0) * K_;
  const unsigned short* Vf = vt16f + (size_t)bh * 49152 + lane * 8;

  f32x4 acc[6];
#pragma unroll
  for (int c = 0; c < 6; c++) acc[c] = (f32x4){0.f, 0.f, 0.f, 0.f};

  for (int kk = 0; kk < 16; kk++) {
    bf16x8 a = *(const bf16x8*)(A + (size_t)lr * K_ + kk * 32 + lg * 8);
#pragma unroll
    for (int c = 0; c < 6; c++) {
      bf16x8 bfr = *(const bf16x8*)(Vf + ((size_t)c * 16 + kk) * 512);
      acc[c] = __builtin_amdgcn_mfma_f32_16x16x32_bf16(a, bfr, acc[c], 0, 0, 0);
    }
  }

  float gamma = gptr[0];
#pragma unroll
  for (int c = 0; c < 6; c++) {
    int fcol = c * 16 + lr;
#pragma unroll
    for (int r = 0; r < 4; r++) {
      int j = row0 + lg * 4 + r;
      size_t oidx = ((size_t)(b * K_ + j)) * D_ + h * DK_ + fcol;
      out[oidx] = gamma * acc[c][r] + fa[oidx];
    }
  }
}

extern "C" void kernel_launch(void* const* d_in, const int* in_sizes, int n_in,
                              void* d_out, int out_size, void* d_ws, size_t ws_size,
                              hipStream_t stream) {
  (void)in_sizes; (void)n_in; (void)out_size; (void)ws_size;
  const float* fa   = (const float*)d_in[0];
  const float* pe   = (const float*)d_in[1];
  const float* wgw  = (const float*)d_in[2];
  const float* wgb  = (const float*)d_in[3];
  const float* wkw  = (const float*)d_in[4];
  const float* wkb  = (const float*)d_in[5];
  const float* wqw  = (const float*)d_in[6];
  const float* wqb  = (const float*)d_in[7];
  const float* wvw  = (const float*)d_in[8];
  const float* wvb  = (const float*)d_in[9];
  const float* gptr = (const float*)d_in[10];
  float* out = (float*)d_out;

  char* ws = (char*)d_ws;
  unsigned short* fa16f = (unsigned short*)ws; ws += (size_t)B_ * K_ * D_ * 2;
  unsigned short* wt16f = (unsigned short*)ws; ws += (size_t)3 * H_ * DK_ * D_ * 2;
  unsigned short* q16f  = (unsigned short*)ws; ws += (size_t)B_ * H_ * K_ * DK_ * 2;
  unsigned short* k16f  = (unsigned short*)ws; ws += (size_t)B_ * H_ * K_ * DK_ * 2;
  unsigned short* vt16f = (unsigned short*)ws; ws += (size_t)B_ * H_ * DK_ * K_ * 2;
  unsigned short* L16   = (unsigned short*)ws; ws += (size_t)B_ * H_ * K_ * K_ * 2;
  unsigned short* p16   = (unsigned short*)ws;

  const int lds_bytes = 32 * GS_PAD * 4;  // 66048 B > 64KB default -> opt in
  hipFuncSetAttribute((const void*)gatesm_kernel,
                      hipFuncAttributeMaxDynamicSharedMemorySize, lds_bytes);

  prep_kernel<<<768 + 144, 256, 0, stream>>>(fa, fa16f, wqw, wkw, wvw, wt16f);
  proj_kernel<<<384, 256, 0, stream>>>(fa16f, wt16f, wqb, wkb, wvb, q16f, k16f, vt16f);
  scores_kernel<<<512, 256, 0, stream>>>(q16f, k16f, L16);
  gatesm_kernel<<<B_ * 128, 512, lds_bytes, stream>>>(pe, wgw, wgb, L16, p16);
  pv_kernel<<<256, 256, 0, stream>>>(p16, vt16f, fa, gptr, out);
}

// Round 23
// 153.956 us; speedup vs baseline: 1.3404x; 1.0042x over previous
//
#include <hip/hip_runtime.h>
#include <hip/hip_bf16.h>

#define B_ 4
#define K_ 512
#define D_ 768
#define DK_ 96
#define DG_ 96
#define H_ 8

typedef __attribute__((ext_vector_type(8))) __bf16 bf16x8;
typedef __attribute__((ext_vector_type(4))) float f32x4;

static __device__ __forceinline__ unsigned short f2bf(float x) {
  union { float f; unsigned int u; } v; v.f = x;
  unsigned int u = v.u;
  return (unsigned short)((u + 0x7FFFu + ((u >> 16) & 1u)) >> 16);
}
static __device__ __forceinline__ float bf2f(unsigned short u) {
  union { unsigned int u; float f; } v; v.u = ((unsigned int)u) << 16;
  return v.f;
}

// ---------------- K0: fused cast f_a -> FRAGMENT-MAJOR bf16  +  W -> FRAGMENT-MAJOR bf16 ----
// Fragment-major: F[rowblk][kk][lane][8] so a wave's MFMA fragment load is
// 64 lanes x contiguous 16B (8 cache lines, coalesced).
__global__ __launch_bounds__(256) void prep_kernel(const float* __restrict__ fa,
                                                   unsigned short* __restrict__ fa16f,
                                                   const float* __restrict__ wq,
                                                   const float* __restrict__ wk,
                                                   const float* __restrict__ wv,
                                                   unsigned short* __restrict__ wt16f) {
  __shared__ unsigned short Ts[96][130];
  if (blockIdx.x < 768) {
    int idx = blockIdx.x * 256 + threadIdx.x;   // 196608 = B*K*D/8 lane-slots
    int row = idx / 96;                          // global row in [0, B*K)
    int d0  = (idx % 96) * 8;
    int rowblk = row >> 4, lr = row & 15;
    int kk = d0 >> 5, lg = (d0 >> 3) & 3;
    const float4* src = (const float4*)(fa + (size_t)row * D_ + d0);
    float4 v0 = src[0], v1 = src[1];
    ushort4 o0, o1;
    o0.x = f2bf(v0.x); o0.y = f2bf(v0.y); o0.z = f2bf(v0.z); o0.w = f2bf(v0.w);
    o1.x = f2bf(v1.x); o1.y = f2bf(v1.y); o1.z = f2bf(v1.z); o1.w = f2bf(v1.w);
    unsigned short* dst = fa16f + (((size_t)rowblk * 24 + kk) * 64 + lg * 16 + lr) * 8;
    ((ushort4*)dst)[0] = o0;
    ((ushort4*)dst)[1] = o1;
  } else {
    int bid = blockIdx.x - 768;                 // 144 blocks: p(3)*h(8)*dt(6)
    int dt = bid % 6; int rest = bid / 6;
    int h = rest % 8; int p = rest / 8;
    int ph = p * 8 + h;
    const float* w = (p == 0) ? wq : (p == 1) ? wk : wv;
    const float* src = w + ((size_t)h * D_ + dt * 128) * DK_;  // 128 d x 96 f, coalesced
    for (int c = threadIdx.x; c < 128 * 96; c += 256) {
      int dd = c / 96, f = c % 96;
      Ts[f][dd] = f2bf(src[c]);
    }
    __syncthreads();
    // write fragment-major: wt16f[ph][cfrag(6)][kk(24)][lane][8]
    for (int c = threadIdx.x; c < 96 * 32; c += 256) {   // 32 ushort4 per f-row
      int f = c / 32, q = c % 32;                        // d_local = q*4
      int kk = dt * 4 + (q >> 3);
      int lg = (q >> 1) & 3;
      int e  = (q & 1) * 4;
      ushort4 v;
      v.x = Ts[f][q * 4 + 0]; v.y = Ts[f][q * 4 + 1];
      v.z = Ts[f][q * 4 + 2]; v.w = Ts[f][q * 4 + 3];
      unsigned short* dst = wt16f +
          ((((size_t)ph * 6 + (f >> 4)) * 24 + kk) * 64 + lg * 16 + (f & 15)) * 8 + e;
      *(ushort4*)dst = v;
    }
  }
}

// ---------------- K1: projections (fragment-major; 64-row tiles for occupancy) ----------------
// grid 768 = 8 XCD x (12 ph-panels x 8 mt); 4 waves x 16 rows each -> 3 waves/SIMD.
// Q/K written fragment-major [bh][rowblk(32)][kk(3)][lane][8] for scores.
// V (p==2) staged through LDS -> vt16f [bh][fblk(6)][kk(16)][lane][8] for pv.
__global__ __launch_bounds__(256) void proj_kernel(
    const unsigned short* __restrict__ fa16f, const unsigned short* __restrict__ wt16f,
    const float* __restrict__ bq, const float* __restrict__ bk, const float* __restrict__ bv,
    unsigned short* __restrict__ q16f, unsigned short* __restrict__ k16f,
    unsigned short* __restrict__ vt16f) {
  __shared__ unsigned short Ts[96][68];    // p==2 epilogue: 64-row tile, stride 68 (8B align)
  int bid = blockIdx.x;
  int xcd = bid & 7, loc = bid >> 3;  // 96 per XCD; bijective over 768
  int b = xcd >> 1, half = xcd & 1;
  int ph = half * 12 + (loc >> 3);    // 12 panels per XCD
  int mt8 = loc & 7;                  // 8 tiles of 64 rows
  int p = ph >> 3, h = ph & 7;
  int lane = threadIdx.x & 63, wid = threadIdx.x >> 6;
  int lr = lane & 15, lg = lane >> 4;
  int rb0 = b * 32 + mt8 * 4 + wid;   // global rowblk (wave owns 16 rows)

  const unsigned short* A  = fa16f + (size_t)rb0 * 24 * 512 + lane * 8;
  const unsigned short* Bt = wt16f + (size_t)ph * 6 * 24 * 512 + lane * 8;

  f32x4 acc[6];
#pragma unroll
  for (int c = 0; c < 6; c++) acc[c] = (f32x4){0.f, 0.f, 0.f, 0.f};

  auto LOADF = [&](bf16x8& a, bf16x8 (&bb)[6], int kk) {
    a = *(const bf16x8*)(A + (size_t)kk * 512);
#pragma unroll
    for (int c = 0; c < 6; c++)
      bb[c] = *(const bf16x8*)(Bt + ((size_t)c * 24 + kk) * 512);
  };
  auto MF = [&](bf16x8& a, bf16x8 (&bb)[6]) {
#pragma unroll
    for (int c = 0; c < 6; c++)
      acc[c] = __builtin_amdgcn_mfma_f32_16x16x32_bf16(a, bb[c], acc[c], 0, 0, 0);
  };

  bf16x8 aX, bX[6], aY, bY[6];
  LOADF(aX, bX, 0);
  for (int kk = 0; kk < 24; kk += 2) {          // 24 K-steps, ping-pong
    LOADF(aY, bY, kk + 1);
    MF(aX, bX);
    if (kk + 2 < 24) LOADF(aX, bX, kk + 2);
    MF(aY, bY);
  }

  const float* bias = (p == 0) ? bq : (p == 1) ? bk : bv;
  if (p == 2) {
    // V: stage 64x96 tile in LDS, write vt16f fragment-major (coalesced 16B/lane)
#pragma unroll
    for (int c = 0; c < 6; c++) {
      int col = c * 16 + lr;
      float bb = bias[h * DK_ + col];
#pragma unroll
      for (int r = 0; r < 4; r++) {
        int lrow = wid * 16 + lg * 4 + r;
        Ts[col][lrow] = f2bf(acc[c][r] + bb);
      }
    }
    __syncthreads();
    unsigned short* dst = vt16f + (size_t)(b * H_ + h) * 49152;
    for (int c2 = threadIdx.x; c2 < 768; c2 += 256) {  // 6 fblk * 2 kkl * 64 lane-slots
      int lane_d = c2 & 63;
      int kkl = (c2 >> 6) & 1;
      int fblk = c2 >> 7;
      int f = fblk * 16 + (lane_d & 15);
      int il = kkl * 32 + (lane_d >> 4) * 8;
      ushort4 v0 = *(const ushort4*)&Ts[f][il];
      ushort4 v1 = *(const ushort4*)&Ts[f][il + 4];
      unsigned short* o = dst + (((size_t)fblk * 16 + (mt8 * 2 + kkl)) * 64 + lane_d) * 8;
      ((ushort4*)o)[0] = v0;
      ((ushort4*)o)[1] = v1;
    }
  } else {
    // Q/K: fragment-major writes for scores' coalesced frag loads
    unsigned short* dst = ((p == 0) ? q16f : k16f) + (size_t)(b * H_ + h) * 49152;
    int rowblk = mt8 * 4 + wid;
#pragma unroll
    for (int c = 0; c < 6; c++) {
      int col = c * 16 + lr;
      int kk = col >> 5, klg = (col >> 3) & 3, e = col & 7;
      float bb = bias[h * DK_ + col];
#pragma unroll
      for (int r = 0; r < 4; r++) {
        int row_lr = lg * 4 + r;
        dst[(((size_t)rowblk * 3 + kk) * 64 + klg * 16 + row_lr) * 8 + e] =
            f2bf(acc[c][r] + bb);
      }
    }
  }
}

// ---------------- K2: scores (fragment-major Q/K loads)  L16 = bf16(q·k/sqrt(96)) ----------------
// grid 512, XCD-swizzled. All frag loads = 64 lanes x contiguous 16B.
__global__ __launch_bounds__(256) void scores_kernel(const unsigned short* __restrict__ q16f,
                                                     const unsigned short* __restrict__ k16f,
                                                     unsigned short* __restrict__ L16) {
  int bid = blockIdx.x;
  int xcd = bid & 7, loc = bid >> 3;      // 64 per XCD
  int bh = ((loc >> 4) << 3) | xcd;       // 4 bh per XCD
  int jt = (loc >> 2) & 3, it = loc & 3;
  int b = bh >> 3, h = bh & 7;
  int lane = threadIdx.x & 63, wid = threadIdx.x >> 6;
  int lr = lane & 15, lg = lane >> 4;
  int j0 = jt * 128 + wid * 32;
  int i0 = it * 128;
  const unsigned short* Qf = q16f + (size_t)bh * 49152 + lane * 8;
  const unsigned short* Kf = k16f + (size_t)bh * 49152 + lane * 8;
  int jb0 = jt * 8 + wid * 2;

  f32x4 acc[2][8];
#pragma unroll
  for (int x = 0; x < 2; x++)
#pragma unroll
    for (int c = 0; c < 8; c++) acc[x][c] = (f32x4){0.f, 0.f, 0.f, 0.f};

#pragma unroll
  for (int kk = 0; kk < 3; kk++) {
    bf16x8 a0 = *(const bf16x8*)(Qf + ((size_t)(jb0 + 0) * 3 + kk) * 512);
    bf16x8 a1 = *(const bf16x8*)(Qf + ((size_t)(jb0 + 1) * 3 + kk) * 512);
#pragma unroll
    for (int c = 0; c < 8; c++) {
      bf16x8 bfr = *(const bf16x8*)(Kf + ((size_t)(it * 8 + c) * 3 + kk) * 512);
      acc[0][c] = __builtin_amdgcn_mfma_f32_16x16x32_bf16(a0, bfr, acc[0][c], 0, 0, 0);
      acc[1][c] = __builtin_amdgcn_mfma_f32_16x16x32_bf16(a1, bfr, acc[1][c], 0, 0, 0);
    }
  }

  const float scale = 0.10206207261596577f;  // 1/sqrt(96)
  unsigned short* Lb = L16 + ((size_t)bh * K_ + j0) * K_ + i0;
#pragma unroll
  for (int x = 0; x < 2; x++)
#pragma unroll
    for (int c = 0; c < 8; c++)
#pragma unroll
      for (int r = 0; r < 4; r++) {
        int jl = x * 16 + lg * 4 + r;
        int il = c * 16 + lr;
        Lb[(size_t)jl * K_ + il] = f2bf(acc[x][c][r] * scale);
      }
}

// ---------------- K3: fused gate + softmax (R4 structure; L read as bf16) ----------------
// grid: b(4) * jslab(128), jslab = 4 j-columns; 512 threads.
// LDS: gate-logits [32 rows][516 pad] fp32 = 66 KB -> 2 blocks/CU.
#define GS_PAD 516
__global__ __launch_bounds__(512) void gatesm_kernel(
    const float* __restrict__ pe, const float* __restrict__ wgw,
    const float* __restrict__ wgb, const unsigned short* __restrict__ L16,
    unsigned short* __restrict__ p16) {
  extern __shared__ float Ls[];
  int b = blockIdx.x >> 7;
  int j0 = (blockIdx.x & 127) * 4;
  int t = threadIdx.x;
  int wv = t >> 6, lane = t & 63;
  int lr3 = (lane >> 3) & 7;   // row-in-pass
  int lg3 = lane & 7;          // g-chunk (of 24 float4 chunks, this lane does lg3, lg3+8, lg3+16)
  const float4* pe4 = (const float4*)pe;
  const float4* wg4 = (const float4*)wgw;

  // --- Phase A: gate logits -> LDS ---
  for (int p = 0; p < 8; p++) {
    int i = wv * 64 + p * 8 + lr3;
    float4 pev[4][3];
#pragma unroll
    for (int j = 0; j < 4; j++) {
      size_t base = ((size_t)(b * K_ + i) * K_ + (j0 + j)) * (DG_ / 4);
#pragma unroll
      for (int c = 0; c < 3; c++) pev[j][c] = pe4[base + lg3 + 8 * c];
    }
#pragma unroll
    for (int h = 0; h < H_; h++) {
      float4 w0 = wg4[h * 24 + lg3];
      float4 w1 = wg4[h * 24 + lg3 + 8];
      float4 w2 = wg4[h * 24 + lg3 + 16];
      float bias = wgb[h];
      float acc[4];
#pragma unroll
      for (int j = 0; j < 4; j++) {
        acc[j] = pev[j][0].x * w0.x + pev[j][0].y * w0.y + pev[j][0].z * w0.z + pev[j][0].w * w0.w
               + pev[j][1].x * w1.x + pev[j][1].y * w1.y + pev[j][1].z * w1.z + pev[j][1].w * w1.w
               + pev[j][2].x * w2.x + pev[j][2].y * w2.y + pev[j][2].z * w2.z + pev[j][2].w * w2.w;
      }
#pragma unroll
      for (int j = 0; j < 4; j++) {
        acc[j] += __shfl_xor(acc[j], 1);
        acc[j] += __shfl_xor(acc[j], 2);
        acc[j] += __shfl_xor(acc[j], 4);
      }
      if (lg3 == h) {   // h is a literal per unrolled iteration -> static predication
#pragma unroll
        for (int j = 0; j < 4; j++) {
          float lgt = __logf(fmaxf(acc[j] + bias, 1e-6f));  // relu+clip == max(.,1e-6)
          Ls[(h * 4 + j) * GS_PAD + i] = lgt;
        }
      }
    }
  }
  __syncthreads();

  // --- Phase B: logits = LDS gate + bf16 global scores; softmax over i; write p16 ---
#pragma unroll
  for (int rr = 0; rr < 4; rr++) {
    int row = wv * 4 + rr;          // 32 rows = (h, j)
    int h = row >> 2, j = row & 3;
    const float* Lr = &Ls[row * GS_PAD];
    const unsigned short* Lg = L16 + ((size_t)(b * H_ + h) * K_ + (j0 + j)) * K_;
    float4 g0 = *(const float4*)(Lr + lane * 4);
    float4 g1 = *(const float4*)(Lr + 256 + lane * 4);
    ushort4 s0 = *(const ushort4*)(Lg + lane * 4);
    ushort4 s1 = *(const ushort4*)(Lg + 256 + lane * 4);
    float l0 = g0.x + bf2f(s0.x), l1 = g0.y + bf2f(s0.y);
    float l2 = g0.z + bf2f(s0.z), l3 = g0.w + bf2f(s0.w);
    float l4 = g1.x + bf2f(s1.x), l5 = g1.y + bf2f(s1.y);
    float l6 = g1.z + bf2f(s1.z), l7 = g1.w + bf2f(s1.w);
    float m = fmaxf(fmaxf(fmaxf(l0, l1), fmaxf(l2, l3)),
                    fmaxf(fmaxf(l4, l5), fmaxf(l6, l7)));
#pragma unroll
    for (int o = 32; o > 0; o >>= 1) m = fmaxf(m, __shfl_xor(m, o));
    float e0 = __expf(l0 - m), e1 = __expf(l1 - m), e2 = __expf(l2 - m), e3 = __expf(l3 - m);
    float e4 = __expf(l4 - m), e5 = __expf(l5 - m), e6 = __expf(l6 - m), e7 = __expf(l7 - m);
    float s = ((e0 + e1) + (e2 + e3)) + ((e4 + e5) + (e6 + e7));
#pragma unroll
    for (int o = 32; o > 0; o >>= 1) s += __shfl_xor(s, o);
    float inv = 1.0f / s;
    ushort4 o0, o1;
    o0.x = f2bf(e0 * inv); o0.y = f2bf(e1 * inv); o0.z = f2bf(e2 * inv); o0.w = f2bf(e3 * inv);
    o1.x = f2bf(e4 * inv); o1.y = f2bf(e5 * inv); o1.z = f2bf(e6 * inv); o1.w = f2bf(e7 * inv);
    ushort4* dst = (ushort4*)(p16 + ((size_t)(b * H_ + h) * K_ + (j0 + j)) * K_);
    dst[lane] = o0;
    dst[lane + 64] = o1;
  }
}

// ---------------- K5: PV GEMM + epilogue (fragment-major V, ping-pong prefetch) ----------------
// grid 256, XCD-swizzled. out = gamma*(attn·v)+f_a.
__global__ __launch_bounds__(256) void pv_kernel(const unsigned short* __restrict__ p16,
                                                 const unsigned short* __restrict__ vt16f,
                                                 const float* __restrict__ fa,
                                                 const float* __restrict__ gptr,
                                                 float* __restrict__ out) {
  int bid = blockIdx.x;
  int xcd = bid & 7, loc = bid >> 3;      // 32 per XCD
  int bh = ((loc >> 3) << 3) | xcd;       // 4 bh per XCD
  int mt = loc & 7;
  int b = bh >> 3, h = bh & 7;
  int lane = threadIdx.x & 63, wid = threadIdx.x >> 6;
  int lr = lane & 15, lg = lane >> 4;
  int row0 = mt * 64 + wid * 16;
  const unsigned short* A  = p16 + ((size_t)bh * K_ + row0) * K_;
  const unsigned short* Vf = vt16f + (size_t)bh * 49152 + lane * 8;

  f32x4 acc[6];
#pragma unroll
  for (int c = 0; c < 6; c++) acc[c] = (f32x4){0.f, 0.f, 0.f, 0.f};

  auto LOADF = [&](bf16x8& a, bf16x8 (&bb)[6], int kk) {
    a = *(const bf16x8*)(A + (size_t)lr * K_ + kk * 32 + lg * 8);
#pragma unroll
    for (int c = 0; c < 6; c++)
      bb[c] = *(const bf16x8*)(Vf + ((size_t)c * 16 + kk) * 512);
  };
  auto MF = [&](bf16x8& a, bf16x8 (&bb)[6]) {
#pragma unroll
    for (int c = 0; c < 6; c++)
      acc[c] = __builtin_amdgcn_mfma_f32_16x16x32_bf16(a, bb[c], acc[c], 0, 0, 0);
  };

  bf16x8 aX, bX[6], aY, bY[6];
  LOADF(aX, bX, 0);
  for (int kk = 0; kk < 16; kk += 2) {
    LOADF(aY, bY, kk + 1);
    MF(aX, bX);
    if (kk + 2 < 16) LOADF(aX, bX, kk + 2);
    MF(aY, bY);
  }

  float gamma = gptr[0];
#pragma unroll
  for (int c = 0; c < 6; c++) {
    int fcol = c * 16 + lr;
#pragma unroll
    for (int r = 0; r < 4; r++) {
      int j = row0 + lg * 4 + r;
      size_t oidx = ((size_t)(b * K_ + j)) * D_ + h * DK_ + fcol;
      out[oidx] = gamma * acc[c][r] + fa[oidx];
    }
  }
}

extern "C" void kernel_launch(void* const* d_in, const int* in_sizes, int n_in,
                              void* d_out, int out_size, void* d_ws, size_t ws_size,
                              hipStream_t stream) {
  (void)in_sizes; (void)n_in; (void)out_size; (void)ws_size;
  const float* fa   = (const float*)d_in[0];
  const float* pe   = (const float*)d_in[1];
  const float* wgw  = (const float*)d_in[2];
  const float* wgb  = (const float*)d_in[3];
  const float* wkw  = (const float*)d_in[4];
  const float* wkb  = (const float*)d_in[5];
  const float* wqw  = (const float*)d_in[6];
  const float* wqb  = (const float*)d_in[7];
  const float* wvw  = (const float*)d_in[8];
  const float* wvb  = (const float*)d_in[9];
  const float* gptr = (const float*)d_in[10];
  float* out = (float*)d_out;

  char* ws = (char*)d_ws;
  unsigned short* fa16f = (unsigned short*)ws; ws += (size_t)B_ * K_ * D_ * 2;
  unsigned short* wt16f = (unsigned short*)ws; ws += (size_t)3 * H_ * DK_ * D_ * 2;
  unsigned short* q16f  = (unsigned short*)ws; ws += (size_t)B_ * H_ * K_ * DK_ * 2;
  unsigned short* k16f  = (unsigned short*)ws; ws += (size_t)B_ * H_ * K_ * DK_ * 2;
  unsigned short* vt16f = (unsigned short*)ws; ws += (size_t)B_ * H_ * DK_ * K_ * 2;
  unsigned short* L16   = (unsigned short*)ws; ws += (size_t)B_ * H_ * K_ * K_ * 2;
  unsigned short* p16   = (unsigned short*)ws;

  const int lds_bytes = 32 * GS_PAD * 4;  // 66048 B > 64KB default -> opt in
  hipFuncSetAttribute((const void*)gatesm_kernel,
                      hipFuncAttributeMaxDynamicSharedMemorySize, lds_bytes);

  prep_kernel<<<768 + 144, 256, 0, stream>>>(fa, fa16f, wqw, wkw, wvw, wt16f);
  proj_kernel<<<768, 256, 0, stream>>>(fa16f, wt16f, wqb, wkb, wvb, q16f, k16f, vt16f);
  scores_kernel<<<512, 256, 0, stream>>>(q16f, k16f, L16);
  gatesm_kernel<<<B_ * 128, 512, lds_bytes, stream>>>(pe, wgw, wgb, L16, p16);
  pv_kernel<<<256, 256, 0, stream>>>(p16, vt16f, fa, gptr, out);
}